// Round 7
// baseline (84.188 us; speedup 1.0000x reference)
//
#include <hip/hip_runtime.h>
#include <math.h>

#define N_PTS 8192
#define KNN 16

typedef __attribute__((ext_vector_type(8))) short bf16x8;
typedef __attribute__((ext_vector_type(4))) float f32x4v;

__device__ __forceinline__ unsigned short f2bf(float f)
{
    unsigned u = __float_as_uint(f);
    u = u + 0x7fffu + ((u >> 16) & 1u);       // round-to-nearest-even
    return (unsigned short)(u >> 16);
}
__device__ __forceinline__ unsigned pack2(float a, float b)
{
    return (unsigned)f2bf(a) | ((unsigned)f2bf(b) << 16);
}
__device__ __forceinline__ float rfl(float x)   // force block-uniform value to SGPR
{
    return __int_as_float(__builtin_amdgcn_readfirstlane(__float_as_int(x)));
}

// ---------------------------------------------------------------------------
// prep_all: blocks 0..87 pack weights into MFMA B-frag layout; blocks 88..119
// build pos4 = (x,y,z,|p|^2).
// ---------------------------------------------------------------------------
__global__ __launch_bounds__(256) void prep_all(
    const float* __restrict__ pos, float4* __restrict__ pos4,
    const float* __restrict__ w1a, const float* __restrict__ w1b,
    const float* __restrict__ w2a, const float* __restrict__ w2b,
    const float* __restrict__ w3a, const float* __restrict__ w3b,
    uint4* __restrict__ dst)
{
    const int b = blockIdx.x;
    if (b < 88) {
        if (threadIdx.x >= 64) return;
        const float* Ws[6] = {w1a, w1b, w2a, w2b, w3a, w3b};
        const int Kd[6] = {6, 64, 67, 64, 67, 128};
        const int Nd[6] = {64, 64, 64, 64, 128, 128};
        const int start[7] = {0, 4, 12, 24, 32, 56, 88};
        int m = 0;
        while (b >= start[m + 1]) ++m;
        const int f  = b - start[m];
        const int NT = Nd[m] / 16;
        const int ks = f / NT, nt = f % NT;
        const int lane = threadIdx.x;
        const int c  = nt * 16 + (lane & 15);
        const int k0 = ks * 32 + (lane >> 4) * 8;
        const int K = Kd[m], N = Nd[m];
        const float* W = Ws[m];
        float v[8];
#pragma unroll
        for (int j = 0; j < 8; ++j) {
            const int kk = k0 + j;
            v[j] = (kk < K) ? W[kk * N + c] : 0.0f;
        }
        uint4 o;
        o.x = pack2(v[0], v[1]); o.y = pack2(v[2], v[3]);
        o.z = pack2(v[4], v[5]); o.w = pack2(v[6], v[7]);
        dst[b * 64 + lane] = o;
    } else {
        const int i = (b - 88) * 256 + threadIdx.x;
        const float x = pos[i * 3 + 0];
        const float y = pos[i * 3 + 1];
        const float z = pos[i * 3 + 2];
        pos4[i] = make_float4(x, y, z, fmaf(x, x, fmaf(y, y, z * z)));
    }
}

// ---------------------------------------------------------------------------
// kNN threshold-select. Block = 16 queries (SGPR-resident, pre-scaled by -2),
// 4 waves; wave w scans chunk [w*2048,(w+1)*2048) for all 16 queries with an
// explicit 4-deep load pipeline (prefetch next 4 candidates while processing
// current 4 -> 256 VALU inst per 4 loads, latency hidden in-wave).
// Metric s = |p|^2 - 2 q.p (monotone in d2 per query). T = 16th smallest of
// the 64 combined lane-partition minima (bitonic over lanes; partitions are
// j%64 == lane, identical across waves) -> upper bound on true 16th distance.
// Pass 2 collects s <= T (exp ~20, CAP=128); exact top-16 via LDS rank-select
// on unique keys (sortkey(s)<<32 | j), ties broken by lowest index.
// ---------------------------------------------------------------------------
__device__ __forceinline__ unsigned sortkey(const float d2)
{
    unsigned u = __float_as_uint(d2);
    u ^= (unsigned)((int)u >> 31) | 0x80000000u;
    return u;
}

constexpr int CAP = 128;
constexpr int QB  = 16;     // queries per block
constexpr int QW  = QB / 4; // queries finalized per wave

__global__ __launch_bounds__(256) void knn_kernel(const float4* __restrict__ pos4,
                                                  int* __restrict__ idx_out)
{
    __shared__ float mins[QB][4][64];              // 16 KB
    __shared__ float Ts[QB];
    __shared__ unsigned long long surv[QB][CAP];   // 16 KB
    __shared__ int scnt[QB];

    const int tid   = threadIdx.x;
    const int w     = tid >> 6;
    const int lane  = tid & 63;
    const int qbase = blockIdx.x * QB;
    const int cbase = w * (N_PTS / 4);

    if (tid < QB) scnt[tid] = 0;

    float qx[QB], qy[QB], qz[QB];
#pragma unroll
    for (int qi = 0; qi < QB; ++qi) {
        const float4 qp = pos4[qbase + qi];
        qx[qi] = rfl(-2.0f * qp.x);
        qy[qi] = rfl(-2.0f * qp.y);
        qz[qi] = rfl(-2.0f * qp.z);
    }

    float mn[QB];
#pragma unroll
    for (int qi = 0; qi < QB; ++qi) mn[qi] = 1e30f;

    const float4* cp = pos4 + cbase + lane;

    // ---- pass 1: per-lane min of s, 4-deep software pipeline ----
    {
        float4 c0 = cp[0 * 64], c1 = cp[1 * 64], c2 = cp[2 * 64], c3 = cp[3 * 64];
#pragma unroll 1
        for (int t = 0; t < 28; t += 4) {
            const float4 n0 = cp[(t + 4) * 64];
            const float4 n1 = cp[(t + 5) * 64];
            const float4 n2 = cp[(t + 6) * 64];
            const float4 n3 = cp[(t + 7) * 64];
#pragma unroll
            for (int qi = 0; qi < QB; ++qi) {
                mn[qi] = fminf(mn[qi], fmaf(qx[qi], c0.x, fmaf(qy[qi], c0.y, fmaf(qz[qi], c0.z, c0.w))));
                mn[qi] = fminf(mn[qi], fmaf(qx[qi], c1.x, fmaf(qy[qi], c1.y, fmaf(qz[qi], c1.z, c1.w))));
                mn[qi] = fminf(mn[qi], fmaf(qx[qi], c2.x, fmaf(qy[qi], c2.y, fmaf(qz[qi], c2.z, c2.w))));
                mn[qi] = fminf(mn[qi], fmaf(qx[qi], c3.x, fmaf(qy[qi], c3.y, fmaf(qz[qi], c3.z, c3.w))));
            }
            c0 = n0; c1 = n1; c2 = n2; c3 = n3;
        }
#pragma unroll
        for (int qi = 0; qi < QB; ++qi) {
            mn[qi] = fminf(mn[qi], fmaf(qx[qi], c0.x, fmaf(qy[qi], c0.y, fmaf(qz[qi], c0.z, c0.w))));
            mn[qi] = fminf(mn[qi], fmaf(qx[qi], c1.x, fmaf(qy[qi], c1.y, fmaf(qz[qi], c1.z, c1.w))));
            mn[qi] = fminf(mn[qi], fmaf(qx[qi], c2.x, fmaf(qy[qi], c2.y, fmaf(qz[qi], c2.z, c2.w))));
            mn[qi] = fminf(mn[qi], fmaf(qx[qi], c3.x, fmaf(qy[qi], c3.y, fmaf(qz[qi], c3.z, c3.w))));
        }
    }
#pragma unroll
    for (int qi = 0; qi < QB; ++qi) mins[qi][w][lane] = mn[qi];
    __syncthreads();

    // ---- T per query: wave w sorts queries w*QW..w*QW+QW-1 (bitonic) ----
#pragma unroll
    for (int k = 0; k < QW; ++k) {
        const int q = w * QW + k;
        float v = fminf(fminf(mins[q][0][lane], mins[q][1][lane]),
                        fminf(mins[q][2][lane], mins[q][3][lane]));
#pragma unroll
        for (int kk = 2; kk <= 64; kk <<= 1)
#pragma unroll
            for (int j = kk >> 1; j > 0; j >>= 1) {
                const float o = __shfl_xor(v, j);
                const bool up = ((lane & kk) == 0);
                const bool lo = ((lane & j) == 0);
                v = (up == lo) ? fminf(v, o) : fmaxf(v, o);
            }
        if (lane == 15) Ts[q] = v;
    }
    __syncthreads();

    float T[QB];
#pragma unroll
    for (int qi = 0; qi < QB; ++qi) T[qi] = rfl(Ts[qi]);

    // ---- pass 2: collect survivors (4-deep pipeline) ----
    {
        float4 c0 = cp[0 * 64], c1 = cp[1 * 64], c2 = cp[2 * 64], c3 = cp[3 * 64];
#pragma unroll 1
        for (int t = 0; t < 32; t += 4) {
            float4 n0, n1, n2, n3;
            if (t + 4 < 32) {
                n0 = cp[(t + 4) * 64]; n1 = cp[(t + 5) * 64];
                n2 = cp[(t + 6) * 64]; n3 = cp[(t + 7) * 64];
            }
#pragma unroll
            for (int u = 0; u < 4; ++u) {
                const float4 p = (u == 0) ? c0 : (u == 1) ? c1 : (u == 2) ? c2 : c3;
                const int j = cbase + (t + u) * 64 + lane;
#pragma unroll
                for (int qi = 0; qi < QB; ++qi) {
                    const float s = fmaf(qx[qi], p.x, fmaf(qy[qi], p.y, fmaf(qz[qi], p.z, p.w)));
                    if (s <= T[qi]) {
                        const int slot = atomicAdd(&scnt[qi], 1);
                        if (slot < CAP)
                            surv[qi][slot] = ((unsigned long long)sortkey(s) << 32) | (unsigned)j;
                    }
                }
            }
            if (t + 4 < 32) { c0 = n0; c1 = n1; c2 = n2; c3 = n3; }
        }
    }
    __syncthreads();

    // ---- exact top-16 by rank-select: rank = #{key < mine} (keys unique) ----
    for (int k = 0; k < QW; ++k) {
        const int q = w * QW + k;
        const int n = min(scnt[q], CAP);
        const unsigned long long k0 = (lane < n) ? surv[q][lane] : ~0ull;
        const unsigned long long k1 = (lane + 64 < n) ? surv[q][lane + 64] : ~0ull;
        int r0 = 0, r1 = 0;
        for (int e = 0; e < n; ++e) {
            const unsigned long long ke = surv[q][e];   // LDS broadcast read
            r0 += (ke < k0) ? 1 : 0;
            r1 += (ke < k1) ? 1 : 0;
        }
        if (lane < n && r0 < KNN)
            idx_out[(qbase + q) * KNN + r0] = (int)(unsigned)(k0 & 0xFFFFFFFFu);
        if (lane + 64 < n && r1 < KNN)
            idx_out[(qbase + q) * KNN + r1] = (int)(unsigned)(k1 & 0xFFFFFFFFu);
    }
}

// ---------------------------------------------------------------------------
// MFMA PointNetConv with LDS aliasing: msg (stride KP1) and h (stride KP2)
// share one buffer. GEMM1 reads msg -> acc in regs -> barrier -> h stored over
// the same LDS -> barrier -> GEMM2. LDS ~35 KB -> 4 blocks/CU (one dispatch
// round at grid 1024).
// ---------------------------------------------------------------------------
template <int CIN, int CMID, int COUT, int WM, int WN>
__global__ __launch_bounds__(256) void conv_mfma(
    const float* __restrict__ x, const float* __restrict__ pos,
    const int* __restrict__ idx,
    const uint4* __restrict__ fA, const float* __restrict__ ba,
    const uint4* __restrict__ fB, const float* __restrict__ bb,
    float* __restrict__ out)
{
    constexpr int PB  = 8, M = 128;
    constexpr int K1  = (CIN + 3 + 31) & ~31;   // 32 or 96
    constexpr int KS1 = K1 / 32;
    constexpr int KP1 = K1 + 8;
    constexpr int KS2 = CMID / 32;
    constexpr int KP2 = CMID + 8;
    constexpr int NT  = COUT / 16;
    constexpr int NTW = NT / WN;                // 4
    constexpr int MFW = (M / 16) / WM;          // 2 or 4
    constexpr int MSGS = M * KP1;               // shorts
    constexpr int HBS  = M * KP2;               // shorts
    constexpr int BUFS = (MSGS > HBS) ? MSGS : HBS;

    __shared__ int nbr[M];
    __shared__ __align__(16) unsigned short buf[BUFS];

    const int tid  = threadIdx.x;
    const int lane = tid & 63;
    const int w    = tid >> 6;
    const int wm   = w / WN, wn = w % WN;
    const int i0   = blockIdx.x * PB;

    if (tid < M) nbr[tid] = idx[i0 * KNN + tid];
    __syncthreads();

    // ---- build msg (bf16), stride KP1 ----
    if constexpr (CIN == 3) {
        if (tid < M) {
            const int row = tid, p = row >> 4, j = nbr[row];
            const float ax = pos[j * 3 + 0], ay = pos[j * 3 + 1], az = pos[j * 3 + 2];
            const float bx = pos[(i0 + p) * 3 + 0], by = pos[(i0 + p) * 3 + 1],
                        bz = pos[(i0 + p) * 3 + 2];
            uint4 c0;
            c0.x = pack2(ax, ay);
            c0.y = pack2(az, ax - bx);
            c0.z = pack2(ay - by, az - bz);
            c0.w = 0u;
            *reinterpret_cast<uint4*>(&buf[row * KP1 + 0])  = c0;
            const uint4 z = make_uint4(0, 0, 0, 0);
            *reinterpret_cast<uint4*>(&buf[row * KP1 + 8])  = z;
            *reinterpret_cast<uint4*>(&buf[row * KP1 + 16]) = z;
            *reinterpret_cast<uint4*>(&buf[row * KP1 + 24]) = z;
        }
    } else {
        const int row = tid >> 1, hh = tid & 1;
        const int j = nbr[row];
        const float* xr = x + j * CIN + hh * 32;
#pragma unroll
        for (int cc = 0; cc < 32; cc += 8) {
            const float4 f0 = *reinterpret_cast<const float4*>(xr + cc);
            const float4 f1 = *reinterpret_cast<const float4*>(xr + cc + 4);
            uint4 o;
            o.x = pack2(f0.x, f0.y); o.y = pack2(f0.z, f0.w);
            o.z = pack2(f1.x, f1.y); o.w = pack2(f1.z, f1.w);
            *reinterpret_cast<uint4*>(&buf[row * KP1 + hh * 32 + cc]) = o;
        }
        if (hh) {
            const int p = row >> 4;
            const float rx = pos[j * 3 + 0] - pos[(i0 + p) * 3 + 0];
            const float ry = pos[j * 3 + 1] - pos[(i0 + p) * 3 + 1];
            const float rz = pos[j * 3 + 2] - pos[(i0 + p) * 3 + 2];
            uint4 c0;
            c0.x = pack2(rx, ry);
            c0.y = pack2(rz, 0.0f);
            c0.z = 0u; c0.w = 0u;
            *reinterpret_cast<uint4*>(&buf[row * KP1 + 64]) = c0;
            const uint4 z = make_uint4(0, 0, 0, 0);
            *reinterpret_cast<uint4*>(&buf[row * KP1 + 72]) = z;
            *reinterpret_cast<uint4*>(&buf[row * KP1 + 80]) = z;
            *reinterpret_cast<uint4*>(&buf[row * KP1 + 88]) = z;
        }
    }
    __syncthreads();

    // ---- GEMM1: acc = msg @ Wa (acc stays in regs) ----
    f32x4v acc[MFW][NTW];
    {
        uint4 b1[KS1][NTW];
#pragma unroll
        for (int ks = 0; ks < KS1; ++ks)
#pragma unroll
            for (int nt = 0; nt < NTW; ++nt)
                b1[ks][nt] = fA[(ks * NT + wn * NTW + nt) * 64 + lane];

#pragma unroll
        for (int mf = 0; mf < MFW; ++mf)
#pragma unroll
            for (int nt = 0; nt < NTW; ++nt) acc[mf][nt] = (f32x4v)0.0f;

#pragma unroll
        for (int mf = 0; mf < MFW; ++mf) {
            bf16x8 a[KS1];
#pragma unroll
            for (int ks = 0; ks < KS1; ++ks)
                a[ks] = *reinterpret_cast<const bf16x8*>(
                    &buf[((wm * MFW + mf) * 16 + (lane & 15)) * KP1 + ks * 32 + (lane >> 4) * 8]);
#pragma unroll
            for (int nt = 0; nt < NTW; ++nt)
#pragma unroll
                for (int ks = 0; ks < KS1; ++ks)
                    acc[mf][nt] = __builtin_amdgcn_mfma_f32_16x16x32_bf16(
                        a[ks], __builtin_bit_cast(bf16x8, b1[ks][nt]), acc[mf][nt], 0, 0, 0);
        }
    }
    __syncthreads();    // all msg reads complete before h overwrites buf

    {   // ---- store h = relu(acc + ba) as bf16, stride KP2 ----
        float bav[NTW];
#pragma unroll
        for (int nt = 0; nt < NTW; ++nt) bav[nt] = ba[(wn * NTW + nt) * 16 + (lane & 15)];
#pragma unroll
        for (int mf = 0; mf < MFW; ++mf)
#pragma unroll
            for (int nt = 0; nt < NTW; ++nt)
#pragma unroll
                for (int r = 0; r < 4; ++r) {
                    const float v = fmaxf(acc[mf][nt][r] + bav[nt], 0.0f);
                    buf[((wm * MFW + mf) * 16 + (lane >> 4) * 4 + r) * KP2 +
                        (wn * NTW + nt) * 16 + (lane & 15)] = f2bf(v);
                }
    }
    __syncthreads();

    // ---- GEMM2: out = relu(max_k(htile @ Wb) + bb) ----
    {
        uint4 b2[KS2][NTW];
#pragma unroll
        for (int ks = 0; ks < KS2; ++ks)
#pragma unroll
            for (int nt = 0; nt < NTW; ++nt)
                b2[ks][nt] = fB[(ks * NT + wn * NTW + nt) * 64 + lane];

        f32x4v acc2[MFW][NTW];
#pragma unroll
        for (int mf = 0; mf < MFW; ++mf)
#pragma unroll
            for (int nt = 0; nt < NTW; ++nt) acc2[mf][nt] = (f32x4v)0.0f;

#pragma unroll
        for (int mf = 0; mf < MFW; ++mf) {
            bf16x8 a[KS2];
#pragma unroll
            for (int ks = 0; ks < KS2; ++ks)
                a[ks] = *reinterpret_cast<const bf16x8*>(
                    &buf[((wm * MFW + mf) * 16 + (lane & 15)) * KP2 + ks * 32 + (lane >> 4) * 8]);
#pragma unroll
            for (int nt = 0; nt < NTW; ++nt)
#pragma unroll
                for (int ks = 0; ks < KS2; ++ks)
                    acc2[mf][nt] = __builtin_amdgcn_mfma_f32_16x16x32_bf16(
                        a[ks], __builtin_bit_cast(bf16x8, b2[ks][nt]), acc2[mf][nt], 0, 0, 0);
        }

        float bbv[NTW];
#pragma unroll
        for (int nt = 0; nt < NTW; ++nt) bbv[nt] = bb[(wn * NTW + nt) * 16 + (lane & 15)];

#pragma unroll
        for (int mf = 0; mf < MFW; ++mf)
#pragma unroll
            for (int nt = 0; nt < NTW; ++nt) {
                const f32x4v t = acc2[mf][nt];
                float m0 = fmaxf(fmaxf(t[0], t[1]), fmaxf(t[2], t[3]));
                m0 = fmaxf(m0, __shfl_xor(m0, 16));
                m0 = fmaxf(m0, __shfl_xor(m0, 32));
                const float v = fmaxf(m0 + bbv[nt], 0.0f);
                if (lane < 16)
                    out[(i0 + wm * MFW + mf) * COUT + (wn * NTW + nt) * 16 + lane] = v;
            }
    }
}

extern "C" void kernel_launch(void* const* d_in, const int* in_sizes, int n_in,
                              void* d_out, int out_size, void* d_ws, size_t ws_size,
                              hipStream_t stream)
{
    const float* pos = (const float*)d_in[0];
    const float* W1a = (const float*)d_in[1];
    const float* b1a = (const float*)d_in[2];
    const float* W1b = (const float*)d_in[3];
    const float* b1b = (const float*)d_in[4];
    const float* W2a = (const float*)d_in[5];
    const float* b2a = (const float*)d_in[6];
    const float* W2b = (const float*)d_in[7];
    const float* b2b = (const float*)d_in[8];
    const float* W3a = (const float*)d_in[9];
    const float* b3a = (const float*)d_in[10];
    const float* W3b = (const float*)d_in[11];
    const float* b3b = (const float*)d_in[12];

    float* out = (float*)d_out;
    float* h1 = out;                        // 8192 x 64
    float* h2 = out + N_PTS * 64;           // 8192 x 64
    float* h3 = out + N_PTS * 128;          // 8192 x 128

    int*   idx     = (int*)d_ws;                                   // 512 KB
    uint4* wsFrags = (uint4*)((char*)d_ws + N_PTS * KNN * 4);      // 88 KB

    // pos4 scratch in h3 region (dead before conv3 writes h3)
    float4* pos4 = (float4*)h3;

    prep_all<<<120, 256, 0, stream>>>(pos, pos4, W1a, W1b, W2a, W2b, W3a, W3b, wsFrags);
    knn_kernel<<<N_PTS / QB, 256, 0, stream>>>(pos4, idx);

    const uint4* fW1a = wsFrags + 0 * 64;
    const uint4* fW1b = wsFrags + 4 * 64;
    const uint4* fW2a = wsFrags + 12 * 64;
    const uint4* fW2b = wsFrags + 24 * 64;
    const uint4* fW3a = wsFrags + 32 * 64;
    const uint4* fW3b = wsFrags + 56 * 64;

    conv_mfma<3, 64, 64, 4, 1><<<N_PTS / 8, 256, 0, stream>>>(
        pos, pos, idx, fW1a, b1a, fW1b, b1b, h1);
    conv_mfma<64, 64, 64, 4, 1><<<N_PTS / 8, 256, 0, stream>>>(
        h1, pos, idx, fW2a, b2a, fW2b, b2b, h2);
    conv_mfma<64, 128, 128, 2, 2><<<N_PTS / 8, 256, 0, stream>>>(
        h2, pos, idx, fW3a, b3a, fW3b, b3b, h3);
}

// Round 8
// 82.393 us; speedup vs baseline: 1.0218x; 1.0218x over previous
//
#include <hip/hip_runtime.h>
#include <math.h>

#define N_PTS 8192
#define KNN 16

typedef __attribute__((ext_vector_type(8))) short bf16x8;
typedef __attribute__((ext_vector_type(4))) float f32x4v;

__device__ __forceinline__ unsigned short f2bf(float f)
{
    unsigned u = __float_as_uint(f);
    u = u + 0x7fffu + ((u >> 16) & 1u);       // round-to-nearest-even
    return (unsigned short)(u >> 16);
}
__device__ __forceinline__ unsigned pack2(float a, float b)
{
    return (unsigned)f2bf(a) | ((unsigned)f2bf(b) << 16);
}
__device__ __forceinline__ float rfl(float x)   // force block-uniform value to SGPR
{
    return __int_as_float(__builtin_amdgcn_readfirstlane(__float_as_int(x)));
}

// ---------------------------------------------------------------------------
// prep_all: blocks 0..87 pack weights into MFMA B-frag layout; blocks 88..119
// build pos4 = (x,y,z,|p|^2).
// ---------------------------------------------------------------------------
__global__ __launch_bounds__(256) void prep_all(
    const float* __restrict__ pos, float4* __restrict__ pos4,
    const float* __restrict__ w1a, const float* __restrict__ w1b,
    const float* __restrict__ w2a, const float* __restrict__ w2b,
    const float* __restrict__ w3a, const float* __restrict__ w3b,
    uint4* __restrict__ dst)
{
    const int b = blockIdx.x;
    if (b < 88) {
        if (threadIdx.x >= 64) return;
        const float* Ws[6] = {w1a, w1b, w2a, w2b, w3a, w3b};
        const int Kd[6] = {6, 64, 67, 64, 67, 128};
        const int Nd[6] = {64, 64, 64, 64, 128, 128};
        const int start[7] = {0, 4, 12, 24, 32, 56, 88};
        int m = 0;
        while (b >= start[m + 1]) ++m;
        const int f  = b - start[m];
        const int NT = Nd[m] / 16;
        const int ks = f / NT, nt = f % NT;
        const int lane = threadIdx.x;
        const int c  = nt * 16 + (lane & 15);
        const int k0 = ks * 32 + (lane >> 4) * 8;
        const int K = Kd[m], N = Nd[m];
        const float* W = Ws[m];
        float v[8];
#pragma unroll
        for (int j = 0; j < 8; ++j) {
            const int kk = k0 + j;
            v[j] = (kk < K) ? W[kk * N + c] : 0.0f;
        }
        uint4 o;
        o.x = pack2(v[0], v[1]); o.y = pack2(v[2], v[3]);
        o.z = pack2(v[4], v[5]); o.w = pack2(v[6], v[7]);
        dst[b * 64 + lane] = o;
    } else {
        const int i = (b - 88) * 256 + threadIdx.x;
        const float x = pos[i * 3 + 0];
        const float y = pos[i * 3 + 1];
        const float z = pos[i * 3 + 2];
        pos4[i] = make_float4(x, y, z, fmaf(x, x, fmaf(y, y, z * z)));
    }
}

// ---------------------------------------------------------------------------
// kNN threshold-select, full-occupancy edition.
// Block = 512 threads (8 waves), QB=8 queries. Wave w scans candidate chunk
// [w*1024,(w+1)*1024) = 16 groups of 64 for all 8 queries, 4-deep manual
// prefetch. Grid 1024 blocks -> 4 blocks/CU -> 32 waves/CU (100% occupancy;
// __launch_bounds__(512,8) caps VGPR at 64, queries live in SGPRs).
// Metric s = |p|^2 - 2 q.p (monotone in d2 per query). Lane-partition
// (j%64==lane) minima combined across the 8 waves; T = 16th smallest of the
// 64 column minima (wave-bitonic) >= true 16th distance (16 smallest column
// minima are distinct points). Pass 2 collects s <= T (exp ~20-30, CAP=128);
// exact top-16 via LDS rank-select on unique keys (sortkey(s)<<32 | j).
// ---------------------------------------------------------------------------
__device__ __forceinline__ unsigned sortkey(const float d2)
{
    unsigned u = __float_as_uint(d2);
    u ^= (unsigned)((int)u >> 31) | 0x80000000u;
    return u;
}

constexpr int CAP = 128;
constexpr int QB  = 8;      // queries per block
constexpr int NWV = 8;      // waves per block

__global__ __launch_bounds__(512, 8) void knn_kernel(const float4* __restrict__ pos4,
                                                     int* __restrict__ idx_out)
{
    __shared__ float mins[QB][NWV][64];            // 16 KB
    __shared__ float Ts[QB];
    __shared__ unsigned long long surv[QB][CAP];   // 8 KB
    __shared__ int scnt[QB];

    const int tid   = threadIdx.x;
    const int w     = tid >> 6;
    const int lane  = tid & 63;
    const int qbase = blockIdx.x * QB;
    const int cbase = w * (N_PTS / NWV);           // 1024-candidate chunk

    if (tid < QB) scnt[tid] = 0;

    float qx[QB], qy[QB], qz[QB];
#pragma unroll
    for (int qi = 0; qi < QB; ++qi) {
        const float4 qp = pos4[qbase + qi];
        qx[qi] = rfl(-2.0f * qp.x);
        qy[qi] = rfl(-2.0f * qp.y);
        qz[qi] = rfl(-2.0f * qp.z);
    }

    float mn[QB];
#pragma unroll
    for (int qi = 0; qi < QB; ++qi) mn[qi] = 1e30f;

    const float4* cp = pos4 + cbase + lane;

    // ---- pass 1: per-lane min of s over 16 groups, 4-deep pipeline ----
    {
        float4 c0 = cp[0 * 64], c1 = cp[1 * 64], c2 = cp[2 * 64], c3 = cp[3 * 64];
#pragma unroll 1
        for (int t = 0; t < 12; t += 4) {
            const float4 n0 = cp[(t + 4) * 64];
            const float4 n1 = cp[(t + 5) * 64];
            const float4 n2 = cp[(t + 6) * 64];
            const float4 n3 = cp[(t + 7) * 64];
#pragma unroll
            for (int qi = 0; qi < QB; ++qi) {
                mn[qi] = fminf(mn[qi], fmaf(qx[qi], c0.x, fmaf(qy[qi], c0.y, fmaf(qz[qi], c0.z, c0.w))));
                mn[qi] = fminf(mn[qi], fmaf(qx[qi], c1.x, fmaf(qy[qi], c1.y, fmaf(qz[qi], c1.z, c1.w))));
                mn[qi] = fminf(mn[qi], fmaf(qx[qi], c2.x, fmaf(qy[qi], c2.y, fmaf(qz[qi], c2.z, c2.w))));
                mn[qi] = fminf(mn[qi], fmaf(qx[qi], c3.x, fmaf(qy[qi], c3.y, fmaf(qz[qi], c3.z, c3.w))));
            }
            c0 = n0; c1 = n1; c2 = n2; c3 = n3;
        }
#pragma unroll
        for (int qi = 0; qi < QB; ++qi) {
            mn[qi] = fminf(mn[qi], fmaf(qx[qi], c0.x, fmaf(qy[qi], c0.y, fmaf(qz[qi], c0.z, c0.w))));
            mn[qi] = fminf(mn[qi], fmaf(qx[qi], c1.x, fmaf(qy[qi], c1.y, fmaf(qz[qi], c1.z, c1.w))));
            mn[qi] = fminf(mn[qi], fmaf(qx[qi], c2.x, fmaf(qy[qi], c2.y, fmaf(qz[qi], c2.z, c2.w))));
            mn[qi] = fminf(mn[qi], fmaf(qx[qi], c3.x, fmaf(qy[qi], c3.y, fmaf(qz[qi], c3.z, c3.w))));
        }
    }
#pragma unroll
    for (int qi = 0; qi < QB; ++qi) mins[qi][w][lane] = mn[qi];
    __syncthreads();

    // ---- T per query: wave w handles query w (bitonic over 64 lanes) ----
    {
        const int q = w;
        float v = mins[q][0][lane];
#pragma unroll
        for (int k = 1; k < NWV; ++k) v = fminf(v, mins[q][k][lane]);
#pragma unroll
        for (int kk = 2; kk <= 64; kk <<= 1)
#pragma unroll
            for (int j = kk >> 1; j > 0; j >>= 1) {
                const float o = __shfl_xor(v, j);
                const bool up = ((lane & kk) == 0);
                const bool lo = ((lane & j) == 0);
                v = (up == lo) ? fminf(v, o) : fmaxf(v, o);
            }
        if (lane == 15) Ts[q] = v;
    }
    __syncthreads();

    float T[QB];
#pragma unroll
    for (int qi = 0; qi < QB; ++qi) T[qi] = rfl(Ts[qi]);

    // ---- pass 2: collect survivors (4-deep pipeline) ----
    {
        float4 c0 = cp[0 * 64], c1 = cp[1 * 64], c2 = cp[2 * 64], c3 = cp[3 * 64];
#pragma unroll 1
        for (int t = 0; t < 16; t += 4) {
            float4 n0, n1, n2, n3;
            if (t < 12) {
                n0 = cp[(t + 4) * 64]; n1 = cp[(t + 5) * 64];
                n2 = cp[(t + 6) * 64]; n3 = cp[(t + 7) * 64];
            }
#pragma unroll
            for (int u = 0; u < 4; ++u) {
                const float4 p = (u == 0) ? c0 : (u == 1) ? c1 : (u == 2) ? c2 : c3;
                const int j = cbase + (t + u) * 64 + lane;
#pragma unroll
                for (int qi = 0; qi < QB; ++qi) {
                    const float s = fmaf(qx[qi], p.x, fmaf(qy[qi], p.y, fmaf(qz[qi], p.z, p.w)));
                    if (s <= T[qi]) {
                        const int slot = atomicAdd(&scnt[qi], 1);
                        if (slot < CAP)
                            surv[qi][slot] = ((unsigned long long)sortkey(s) << 32) | (unsigned)j;
                    }
                }
            }
            if (t < 12) { c0 = n0; c1 = n1; c2 = n2; c3 = n3; }
        }
    }
    __syncthreads();

    // ---- exact top-16: wave w ranks query w (rank = #{key < mine}) ----
    {
        const int q = w;
        const int n = min(scnt[q], CAP);
        const unsigned long long k0 = (lane < n) ? surv[q][lane] : ~0ull;
        const unsigned long long k1 = (lane + 64 < n) ? surv[q][lane + 64] : ~0ull;
        int r0 = 0, r1 = 0;
#pragma unroll 4
        for (int e = 0; e < n; ++e) {
            const unsigned long long ke = surv[q][e];   // LDS broadcast read
            r0 += (ke < k0) ? 1 : 0;
            r1 += (ke < k1) ? 1 : 0;
        }
        if (lane < n && r0 < KNN)
            idx_out[(qbase + q) * KNN + r0] = (int)(unsigned)(k0 & 0xFFFFFFFFu);
        if (lane + 64 < n && r1 < KNN)
            idx_out[(qbase + q) * KNN + r1] = (int)(unsigned)(k1 & 0xFFFFFFFFu);
    }
}

// ---------------------------------------------------------------------------
// MFMA PointNetConv with LDS aliasing (unchanged from R6): msg (stride KP1)
// and h (stride KP2) share one buffer; GEMM1 accumulates in regs across the
// overwrite barrier. LDS ~35 KB -> 4 blocks/CU.
// ---------------------------------------------------------------------------
template <int CIN, int CMID, int COUT, int WM, int WN>
__global__ __launch_bounds__(256) void conv_mfma(
    const float* __restrict__ x, const float* __restrict__ pos,
    const int* __restrict__ idx,
    const uint4* __restrict__ fA, const float* __restrict__ ba,
    const uint4* __restrict__ fB, const float* __restrict__ bb,
    float* __restrict__ out)
{
    constexpr int PB  = 8, M = 128;
    constexpr int K1  = (CIN + 3 + 31) & ~31;   // 32 or 96
    constexpr int KS1 = K1 / 32;
    constexpr int KP1 = K1 + 8;
    constexpr int KS2 = CMID / 32;
    constexpr int KP2 = CMID + 8;
    constexpr int NT  = COUT / 16;
    constexpr int NTW = NT / WN;                // 4
    constexpr int MFW = (M / 16) / WM;          // 2 or 4
    constexpr int MSGS = M * KP1;               // shorts
    constexpr int HBS  = M * KP2;               // shorts
    constexpr int BUFS = (MSGS > HBS) ? MSGS : HBS;

    __shared__ int nbr[M];
    __shared__ __align__(16) unsigned short buf[BUFS];

    const int tid  = threadIdx.x;
    const int lane = tid & 63;
    const int w    = tid >> 6;
    const int wm   = w / WN, wn = w % WN;
    const int i0   = blockIdx.x * PB;

    if (tid < M) nbr[tid] = idx[i0 * KNN + tid];
    __syncthreads();

    // ---- build msg (bf16), stride KP1 ----
    if constexpr (CIN == 3) {
        if (tid < M) {
            const int row = tid, p = row >> 4, j = nbr[row];
            const float ax = pos[j * 3 + 0], ay = pos[j * 3 + 1], az = pos[j * 3 + 2];
            const float bx = pos[(i0 + p) * 3 + 0], by = pos[(i0 + p) * 3 + 1],
                        bz = pos[(i0 + p) * 3 + 2];
            uint4 c0;
            c0.x = pack2(ax, ay);
            c0.y = pack2(az, ax - bx);
            c0.z = pack2(ay - by, az - bz);
            c0.w = 0u;
            *reinterpret_cast<uint4*>(&buf[row * KP1 + 0])  = c0;
            const uint4 z = make_uint4(0, 0, 0, 0);
            *reinterpret_cast<uint4*>(&buf[row * KP1 + 8])  = z;
            *reinterpret_cast<uint4*>(&buf[row * KP1 + 16]) = z;
            *reinterpret_cast<uint4*>(&buf[row * KP1 + 24]) = z;
        }
    } else {
        const int row = tid >> 1, hh = tid & 1;
        const int j = nbr[row];
        const float* xr = x + j * CIN + hh * 32;
#pragma unroll
        for (int cc = 0; cc < 32; cc += 8) {
            const float4 f0 = *reinterpret_cast<const float4*>(xr + cc);
            const float4 f1 = *reinterpret_cast<const float4*>(xr + cc + 4);
            uint4 o;
            o.x = pack2(f0.x, f0.y); o.y = pack2(f0.z, f0.w);
            o.z = pack2(f1.x, f1.y); o.w = pack2(f1.z, f1.w);
            *reinterpret_cast<uint4*>(&buf[row * KP1 + hh * 32 + cc]) = o;
        }
        if (hh) {
            const int p = row >> 4;
            const float rx = pos[j * 3 + 0] - pos[(i0 + p) * 3 + 0];
            const float ry = pos[j * 3 + 1] - pos[(i0 + p) * 3 + 1];
            const float rz = pos[j * 3 + 2] - pos[(i0 + p) * 3 + 2];
            uint4 c0;
            c0.x = pack2(rx, ry);
            c0.y = pack2(rz, 0.0f);
            c0.z = 0u; c0.w = 0u;
            *reinterpret_cast<uint4*>(&buf[row * KP1 + 64]) = c0;
            const uint4 z = make_uint4(0, 0, 0, 0);
            *reinterpret_cast<uint4*>(&buf[row * KP1 + 72]) = z;
            *reinterpret_cast<uint4*>(&buf[row * KP1 + 80]) = z;
            *reinterpret_cast<uint4*>(&buf[row * KP1 + 88]) = z;
        }
    }
    __syncthreads();

    // ---- GEMM1: acc = msg @ Wa (acc stays in regs) ----
    f32x4v acc[MFW][NTW];
    {
        uint4 b1[KS1][NTW];
#pragma unroll
        for (int ks = 0; ks < KS1; ++ks)
#pragma unroll
            for (int nt = 0; nt < NTW; ++nt)
                b1[ks][nt] = fA[(ks * NT + wn * NTW + nt) * 64 + lane];

#pragma unroll
        for (int mf = 0; mf < MFW; ++mf)
#pragma unroll
            for (int nt = 0; nt < NTW; ++nt) acc[mf][nt] = (f32x4v)0.0f;

#pragma unroll
        for (int mf = 0; mf < MFW; ++mf) {
            bf16x8 a[KS1];
#pragma unroll
            for (int ks = 0; ks < KS1; ++ks)
                a[ks] = *reinterpret_cast<const bf16x8*>(
                    &buf[((wm * MFW + mf) * 16 + (lane & 15)) * KP1 + ks * 32 + (lane >> 4) * 8]);
#pragma unroll
            for (int nt = 0; nt < NTW; ++nt)
#pragma unroll
                for (int ks = 0; ks < KS1; ++ks)
                    acc[mf][nt] = __builtin_amdgcn_mfma_f32_16x16x32_bf16(
                        a[ks], __builtin_bit_cast(bf16x8, b1[ks][nt]), acc[mf][nt], 0, 0, 0);
        }
    }
    __syncthreads();    // all msg reads complete before h overwrites buf

    {   // ---- store h = relu(acc + ba) as bf16, stride KP2 ----
        float bav[NTW];
#pragma unroll
        for (int nt = 0; nt < NTW; ++nt) bav[nt] = ba[(wn * NTW + nt) * 16 + (lane & 15)];
#pragma unroll
        for (int mf = 0; mf < MFW; ++mf)
#pragma unroll
            for (int nt = 0; nt < NTW; ++nt)
#pragma unroll
                for (int r = 0; r < 4; ++r) {
                    const float v = fmaxf(acc[mf][nt][r] + bav[nt], 0.0f);
                    buf[((wm * MFW + mf) * 16 + (lane >> 4) * 4 + r) * KP2 +
                        (wn * NTW + nt) * 16 + (lane & 15)] = f2bf(v);
                }
    }
    __syncthreads();

    // ---- GEMM2: out = relu(max_k(htile @ Wb) + bb) ----
    {
        uint4 b2[KS2][NTW];
#pragma unroll
        for (int ks = 0; ks < KS2; ++ks)
#pragma unroll
            for (int nt = 0; nt < NTW; ++nt)
                b2[ks][nt] = fB[(ks * NT + wn * NTW + nt) * 64 + lane];

        f32x4v acc2[MFW][NTW];
#pragma unroll
        for (int mf = 0; mf < MFW; ++mf)
#pragma unroll
            for (int nt = 0; nt < NTW; ++nt) acc2[mf][nt] = (f32x4v)0.0f;

#pragma unroll
        for (int mf = 0; mf < MFW; ++mf) {
            bf16x8 a[KS2];
#pragma unroll
            for (int ks = 0; ks < KS2; ++ks)
                a[ks] = *reinterpret_cast<const bf16x8*>(
                    &buf[((wm * MFW + mf) * 16 + (lane & 15)) * KP2 + ks * 32 + (lane >> 4) * 8]);
#pragma unroll
            for (int nt = 0; nt < NTW; ++nt)
#pragma unroll
                for (int ks = 0; ks < KS2; ++ks)
                    acc2[mf][nt] = __builtin_amdgcn_mfma_f32_16x16x32_bf16(
                        a[ks], __builtin_bit_cast(bf16x8, b2[ks][nt]), acc2[mf][nt], 0, 0, 0);
        }

        float bbv[NTW];
#pragma unroll
        for (int nt = 0; nt < NTW; ++nt) bbv[nt] = bb[(wn * NTW + nt) * 16 + (lane & 15)];

#pragma unroll
        for (int mf = 0; mf < MFW; ++mf)
#pragma unroll
            for (int nt = 0; nt < NTW; ++nt) {
                const f32x4v t = acc2[mf][nt];
                float m0 = fmaxf(fmaxf(t[0], t[1]), fmaxf(t[2], t[3]));
                m0 = fmaxf(m0, __shfl_xor(m0, 16));
                m0 = fmaxf(m0, __shfl_xor(m0, 32));
                const float v = fmaxf(m0 + bbv[nt], 0.0f);
                if (lane < 16)
                    out[(i0 + wm * MFW + mf) * COUT + (wn * NTW + nt) * 16 + lane] = v;
            }
    }
}

extern "C" void kernel_launch(void* const* d_in, const int* in_sizes, int n_in,
                              void* d_out, int out_size, void* d_ws, size_t ws_size,
                              hipStream_t stream)
{
    const float* pos = (const float*)d_in[0];
    const float* W1a = (const float*)d_in[1];
    const float* b1a = (const float*)d_in[2];
    const float* W1b = (const float*)d_in[3];
    const float* b1b = (const float*)d_in[4];
    const float* W2a = (const float*)d_in[5];
    const float* b2a = (const float*)d_in[6];
    const float* W2b = (const float*)d_in[7];
    const float* b2b = (const float*)d_in[8];
    const float* W3a = (const float*)d_in[9];
    const float* b3a = (const float*)d_in[10];
    const float* W3b = (const float*)d_in[11];
    const float* b3b = (const float*)d_in[12];

    float* out = (float*)d_out;
    float* h1 = out;                        // 8192 x 64
    float* h2 = out + N_PTS * 64;           // 8192 x 64
    float* h3 = out + N_PTS * 128;          // 8192 x 128

    int*   idx     = (int*)d_ws;                                   // 512 KB
    uint4* wsFrags = (uint4*)((char*)d_ws + N_PTS * KNN * 4);      // 88 KB

    // pos4 scratch in h3 region (dead before conv3 writes h3)
    float4* pos4 = (float4*)h3;

    prep_all<<<120, 256, 0, stream>>>(pos, pos4, W1a, W1b, W2a, W2b, W3a, W3b, wsFrags);
    knn_kernel<<<N_PTS / QB, 512, 0, stream>>>(pos4, idx);

    const uint4* fW1a = wsFrags + 0 * 64;
    const uint4* fW1b = wsFrags + 4 * 64;
    const uint4* fW2a = wsFrags + 12 * 64;
    const uint4* fW2b = wsFrags + 24 * 64;
    const uint4* fW3a = wsFrags + 32 * 64;
    const uint4* fW3b = wsFrags + 56 * 64;

    conv_mfma<3, 64, 64, 4, 1><<<N_PTS / 8, 256, 0, stream>>>(
        pos, pos, idx, fW1a, b1a, fW1b, b1b, h1);
    conv_mfma<64, 64, 64, 4, 1><<<N_PTS / 8, 256, 0, stream>>>(
        h1, pos, idx, fW2a, b2a, fW2b, b2b, h2);
    conv_mfma<64, 128, 128, 2, 2><<<N_PTS / 8, 256, 0, stream>>>(
        h2, pos, idx, fW3a, b3a, fW3b, b3b, h3);
}

// Round 9
// 76.930 us; speedup vs baseline: 1.0944x; 1.0710x over previous
//
#include <hip/hip_runtime.h>
#include <math.h>

#define N_PTS 8192
#define KNN 16

typedef __attribute__((ext_vector_type(8))) short bf16x8;
typedef __attribute__((ext_vector_type(4))) float f32x4v;

__device__ __forceinline__ unsigned short f2bf(float f)
{
    unsigned u = __float_as_uint(f);
    u = u + 0x7fffu + ((u >> 16) & 1u);       // round-to-nearest-even
    return (unsigned short)(u >> 16);
}
__device__ __forceinline__ unsigned pack2(float a, float b)
{
    return (unsigned)f2bf(a) | ((unsigned)f2bf(b) << 16);
}
__device__ __forceinline__ float rfl(float x)   // force block-uniform value to SGPR
{
    return __int_as_float(__builtin_amdgcn_readfirstlane(__float_as_int(x)));
}
// round toward +inf to bf16 (value stored >= value): upper bound preserved
__device__ __forceinline__ unsigned short bfup(float f)
{
    const unsigned u = __float_as_uint(f);
    return (unsigned short)((u >> 31) ? (u >> 16) : ((u + 0xFFFFu) >> 16));
}
__device__ __forceinline__ float bfex(unsigned short h)
{
    return __uint_as_float((unsigned)h << 16);
}

// ---------------------------------------------------------------------------
// prep_all: blocks 0..87 pack weights into MFMA B-frag layout; blocks 88..119
// build pos4 = (x,y,z,|p|^2).
// ---------------------------------------------------------------------------
__global__ __launch_bounds__(256) void prep_all(
    const float* __restrict__ pos, float4* __restrict__ pos4,
    const float* __restrict__ w1a, const float* __restrict__ w1b,
    const float* __restrict__ w2a, const float* __restrict__ w2b,
    const float* __restrict__ w3a, const float* __restrict__ w3b,
    uint4* __restrict__ dst)
{
    const int b = blockIdx.x;
    if (b < 88) {
        if (threadIdx.x >= 64) return;
        const float* Ws[6] = {w1a, w1b, w2a, w2b, w3a, w3b};
        const int Kd[6] = {6, 64, 67, 64, 67, 128};
        const int Nd[6] = {64, 64, 64, 64, 128, 128};
        const int start[7] = {0, 4, 12, 24, 32, 56, 88};
        int m = 0;
        while (b >= start[m + 1]) ++m;
        const int f  = b - start[m];
        const int NT = Nd[m] / 16;
        const int ks = f / NT, nt = f % NT;
        const int lane = threadIdx.x;
        const int c  = nt * 16 + (lane & 15);
        const int k0 = ks * 32 + (lane >> 4) * 8;
        const int K = Kd[m], N = Nd[m];
        const float* W = Ws[m];
        float v[8];
#pragma unroll
        for (int j = 0; j < 8; ++j) {
            const int kk = k0 + j;
            v[j] = (kk < K) ? W[kk * N + c] : 0.0f;
        }
        uint4 o;
        o.x = pack2(v[0], v[1]); o.y = pack2(v[2], v[3]);
        o.z = pack2(v[4], v[5]); o.w = pack2(v[6], v[7]);
        dst[b * 64 + lane] = o;
    } else {
        const int i = (b - 88) * 256 + threadIdx.x;
        const float x = pos[i * 3 + 0];
        const float y = pos[i * 3 + 1];
        const float z = pos[i * 3 + 2];
        pos4[i] = make_float4(x, y, z, fmaf(x, x, fmaf(y, y, z * z)));
    }
}

// ---------------------------------------------------------------------------
// kNN threshold-select, LDS-staged edition.
// Block = 512 threads (8 waves), QB=8 queries (SGPR-resident, scaled by -2).
// Candidates stream through LDS in 512-point tiles, double-buffered, staged
// with global_load_lds (width 16, linear layout). Wave w consumes group w of
// each tile (cand index = t*512 + w*64 + lane) for all 8 queries: lane
// partition (index % 64 == lane) is preserved, so the threshold argument is
// unchanged: T = 16th smallest of the 64 column minima >= true 16th distance.
// Column minima are combined across waves via bf16 ROUNDED UP (stored >=
// true), so T' >= T remains a valid upper bound; pass 2 ranks by exact f32 s.
// Pass 2 collects s <= T' (exp ~20-30, CAP=128); exact top-16 via LDS
// rank-select on unique keys (sortkey(s)<<32 | j), ties by lowest index.
// Grid 1024 = 4 blocks/CU, LDS ~32 KB, VGPR ~40 -> 32 waves/CU.
// ---------------------------------------------------------------------------
__device__ __forceinline__ unsigned sortkey(const float d2)
{
    unsigned u = __float_as_uint(d2);
    u ^= (unsigned)((int)u >> 31) | 0x80000000u;
    return u;
}

constexpr int CAP   = 128;
constexpr int QB    = 8;      // queries per block
constexpr int NWV   = 8;      // waves per block
constexpr int TILE  = 512;    // candidates per LDS tile
constexpr int NTL   = N_PTS / TILE;   // 16 tiles

__device__ __forceinline__ void stage_tile(const float4* src, float4* dst)
{
    __builtin_amdgcn_global_load_lds(
        (const __attribute__((address_space(1))) void*)src,
        (__attribute__((address_space(3))) void*)dst, 16, 0, 0);
}

__global__ __launch_bounds__(512, 8) void knn_kernel(const float4* __restrict__ pos4,
                                                     int* __restrict__ idx_out)
{
    __shared__ float4 tile[2][TILE];                 // 16 KB
    __shared__ unsigned short minsbf[QB][NWV][64];   // 8 KB
    __shared__ float Ts[QB];
    __shared__ unsigned long long surv[QB][CAP];     // 8 KB
    __shared__ int scnt[QB];

    const int tid   = threadIdx.x;
    const int w     = tid >> 6;
    const int lane  = tid & 63;
    const int qbase = blockIdx.x * QB;

    if (tid < QB) scnt[tid] = 0;

    float qx[QB], qy[QB], qz[QB];
#pragma unroll
    for (int qi = 0; qi < QB; ++qi) {
        const float4 qp = pos4[qbase + qi];
        qx[qi] = rfl(-2.0f * qp.x);
        qy[qi] = rfl(-2.0f * qp.y);
        qz[qi] = rfl(-2.0f * qp.z);
    }

    const float4* src = pos4 + w * 64 + lane;   // this thread's stage source

    float mn[QB];
#pragma unroll
    for (int qi = 0; qi < QB; ++qi) mn[qi] = 1e30f;

    // ---- pass 1: per-lane min of s, LDS double-buffered tiles ----
    stage_tile(src, &tile[0][w * 64]);
    __syncthreads();
#pragma unroll 1
    for (int t = 0; t < NTL; ++t) {
        if (t + 1 < NTL)
            stage_tile(src + (t + 1) * TILE, &tile[(t + 1) & 1][w * 64]);
        const float4 p = tile[t & 1][w * 64 + lane];
#pragma unroll
        for (int qi = 0; qi < QB; ++qi) {
            const float s = fmaf(qx[qi], p.x, fmaf(qy[qi], p.y, fmaf(qz[qi], p.z, p.w)));
            mn[qi] = fminf(mn[qi], s);
        }
        __syncthreads();
    }
#pragma unroll
    for (int qi = 0; qi < QB; ++qi) minsbf[qi][w][lane] = bfup(mn[qi]);
    __syncthreads();

    // ---- T per query: wave w handles query w (bitonic over 64 lanes) ----
    {
        const int q = w;
        float v = bfex(minsbf[q][0][lane]);
#pragma unroll
        for (int k = 1; k < NWV; ++k) v = fminf(v, bfex(minsbf[q][k][lane]));
#pragma unroll
        for (int kk = 2; kk <= 64; kk <<= 1)
#pragma unroll
            for (int j = kk >> 1; j > 0; j >>= 1) {
                const float o = __shfl_xor(v, j);
                const bool up = ((lane & kk) == 0);
                const bool lo = ((lane & j) == 0);
                v = (up == lo) ? fminf(v, o) : fmaxf(v, o);
            }
        if (lane == 15) Ts[q] = v;
    }
    __syncthreads();

    float T[QB];
#pragma unroll
    for (int qi = 0; qi < QB; ++qi) T[qi] = rfl(Ts[qi]);

    // ---- pass 2: collect survivors (same tiling) ----
    stage_tile(src, &tile[0][w * 64]);
    __syncthreads();
#pragma unroll 1
    for (int t = 0; t < NTL; ++t) {
        if (t + 1 < NTL)
            stage_tile(src + (t + 1) * TILE, &tile[(t + 1) & 1][w * 64]);
        const float4 p = tile[t & 1][w * 64 + lane];
        const int j = t * TILE + w * 64 + lane;
#pragma unroll
        for (int qi = 0; qi < QB; ++qi) {
            const float s = fmaf(qx[qi], p.x, fmaf(qy[qi], p.y, fmaf(qz[qi], p.z, p.w)));
            if (s <= T[qi]) {
                const int slot = atomicAdd(&scnt[qi], 1);
                if (slot < CAP)
                    surv[qi][slot] = ((unsigned long long)sortkey(s) << 32) | (unsigned)j;
            }
        }
        __syncthreads();
    }

    // ---- exact top-16: wave w ranks query w (rank = #{key < mine}) ----
    {
        const int q = w;
        const int n = min(scnt[q], CAP);
        const unsigned long long k0 = (lane < n) ? surv[q][lane] : ~0ull;
        const unsigned long long k1 = (lane + 64 < n) ? surv[q][lane + 64] : ~0ull;
        int r0 = 0, r1 = 0;
#pragma unroll 4
        for (int e = 0; e < n; ++e) {
            const unsigned long long ke = surv[q][e];   // LDS broadcast read
            r0 += (ke < k0) ? 1 : 0;
            r1 += (ke < k1) ? 1 : 0;
        }
        if (lane < n && r0 < KNN)
            idx_out[(qbase + q) * KNN + r0] = (int)(unsigned)(k0 & 0xFFFFFFFFu);
        if (lane + 64 < n && r1 < KNN)
            idx_out[(qbase + q) * KNN + r1] = (int)(unsigned)(k1 & 0xFFFFFFFFu);
    }
}

// ---------------------------------------------------------------------------
// MFMA PointNetConv with LDS aliasing (unchanged from R6/R7): msg (stride KP1)
// and h (stride KP2) share one buffer; GEMM1 accumulates in regs across the
// overwrite barrier. LDS ~35 KB -> 4 blocks/CU.
// ---------------------------------------------------------------------------
template <int CIN, int CMID, int COUT, int WM, int WN>
__global__ __launch_bounds__(256) void conv_mfma(
    const float* __restrict__ x, const float* __restrict__ pos,
    const int* __restrict__ idx,
    const uint4* __restrict__ fA, const float* __restrict__ ba,
    const uint4* __restrict__ fB, const float* __restrict__ bb,
    float* __restrict__ out)
{
    constexpr int PB  = 8, M = 128;
    constexpr int K1  = (CIN + 3 + 31) & ~31;   // 32 or 96
    constexpr int KS1 = K1 / 32;
    constexpr int KP1 = K1 + 8;
    constexpr int KS2 = CMID / 32;
    constexpr int KP2 = CMID + 8;
    constexpr int NT  = COUT / 16;
    constexpr int NTW = NT / WN;                // 4
    constexpr int MFW = (M / 16) / WM;          // 2 or 4
    constexpr int MSGS = M * KP1;               // shorts
    constexpr int HBS  = M * KP2;               // shorts
    constexpr int BUFS = (MSGS > HBS) ? MSGS : HBS;

    __shared__ int nbr[M];
    __shared__ __align__(16) unsigned short buf[BUFS];

    const int tid  = threadIdx.x;
    const int lane = tid & 63;
    const int w    = tid >> 6;
    const int wm   = w / WN, wn = w % WN;
    const int i0   = blockIdx.x * PB;

    if (tid < M) nbr[tid] = idx[i0 * KNN + tid];
    __syncthreads();

    // ---- build msg (bf16), stride KP1 ----
    if constexpr (CIN == 3) {
        if (tid < M) {
            const int row = tid, p = row >> 4, j = nbr[row];
            const float ax = pos[j * 3 + 0], ay = pos[j * 3 + 1], az = pos[j * 3 + 2];
            const float bx = pos[(i0 + p) * 3 + 0], by = pos[(i0 + p) * 3 + 1],
                        bz = pos[(i0 + p) * 3 + 2];
            uint4 c0;
            c0.x = pack2(ax, ay);
            c0.y = pack2(az, ax - bx);
            c0.z = pack2(ay - by, az - bz);
            c0.w = 0u;
            *reinterpret_cast<uint4*>(&buf[row * KP1 + 0])  = c0;
            const uint4 z = make_uint4(0, 0, 0, 0);
            *reinterpret_cast<uint4*>(&buf[row * KP1 + 8])  = z;
            *reinterpret_cast<uint4*>(&buf[row * KP1 + 16]) = z;
            *reinterpret_cast<uint4*>(&buf[row * KP1 + 24]) = z;
        }
    } else {
        const int row = tid >> 1, hh = tid & 1;
        const int j = nbr[row];
        const float* xr = x + j * CIN + hh * 32;
#pragma unroll
        for (int cc = 0; cc < 32; cc += 8) {
            const float4 f0 = *reinterpret_cast<const float4*>(xr + cc);
            const float4 f1 = *reinterpret_cast<const float4*>(xr + cc + 4);
            uint4 o;
            o.x = pack2(f0.x, f0.y); o.y = pack2(f0.z, f0.w);
            o.z = pack2(f1.x, f1.y); o.w = pack2(f1.z, f1.w);
            *reinterpret_cast<uint4*>(&buf[row * KP1 + hh * 32 + cc]) = o;
        }
        if (hh) {
            const int p = row >> 4;
            const float rx = pos[j * 3 + 0] - pos[(i0 + p) * 3 + 0];
            const float ry = pos[j * 3 + 1] - pos[(i0 + p) * 3 + 1];
            const float rz = pos[j * 3 + 2] - pos[(i0 + p) * 3 + 2];
            uint4 c0;
            c0.x = pack2(rx, ry);
            c0.y = pack2(rz, 0.0f);
            c0.z = 0u; c0.w = 0u;
            *reinterpret_cast<uint4*>(&buf[row * KP1 + 64]) = c0;
            const uint4 z = make_uint4(0, 0, 0, 0);
            *reinterpret_cast<uint4*>(&buf[row * KP1 + 72]) = z;
            *reinterpret_cast<uint4*>(&buf[row * KP1 + 80]) = z;
            *reinterpret_cast<uint4*>(&buf[row * KP1 + 88]) = z;
        }
    }
    __syncthreads();

    // ---- GEMM1: acc = msg @ Wa (acc stays in regs) ----
    f32x4v acc[MFW][NTW];
    {
        uint4 b1[KS1][NTW];
#pragma unroll
        for (int ks = 0; ks < KS1; ++ks)
#pragma unroll
            for (int nt = 0; nt < NTW; ++nt)
                b1[ks][nt] = fA[(ks * NT + wn * NTW + nt) * 64 + lane];

#pragma unroll
        for (int mf = 0; mf < MFW; ++mf)
#pragma unroll
            for (int nt = 0; nt < NTW; ++nt) acc[mf][nt] = (f32x4v)0.0f;

#pragma unroll
        for (int mf = 0; mf < MFW; ++mf) {
            bf16x8 a[KS1];
#pragma unroll
            for (int ks = 0; ks < KS1; ++ks)
                a[ks] = *reinterpret_cast<const bf16x8*>(
                    &buf[((wm * MFW + mf) * 16 + (lane & 15)) * KP1 + ks * 32 + (lane >> 4) * 8]);
#pragma unroll
            for (int nt = 0; nt < NTW; ++nt)
#pragma unroll
                for (int ks = 0; ks < KS1; ++ks)
                    acc[mf][nt] = __builtin_amdgcn_mfma_f32_16x16x32_bf16(
                        a[ks], __builtin_bit_cast(bf16x8, b1[ks][nt]), acc[mf][nt], 0, 0, 0);
        }
    }
    __syncthreads();    // all msg reads complete before h overwrites buf

    {   // ---- store h = relu(acc + ba) as bf16, stride KP2 ----
        float bav[NTW];
#pragma unroll
        for (int nt = 0; nt < NTW; ++nt) bav[nt] = ba[(wn * NTW + nt) * 16 + (lane & 15)];
#pragma unroll
        for (int mf = 0; mf < MFW; ++mf)
#pragma unroll
            for (int nt = 0; nt < NTW; ++nt)
#pragma unroll
                for (int r = 0; r < 4; ++r) {
                    const float v = fmaxf(acc[mf][nt][r] + bav[nt], 0.0f);
                    buf[((wm * MFW + mf) * 16 + (lane >> 4) * 4 + r) * KP2 +
                        (wn * NTW + nt) * 16 + (lane & 15)] = f2bf(v);
                }
    }
    __syncthreads();

    // ---- GEMM2: out = relu(max_k(htile @ Wb) + bb) ----
    {
        uint4 b2[KS2][NTW];
#pragma unroll
        for (int ks = 0; ks < KS2; ++ks)
#pragma unroll
            for (int nt = 0; nt < NTW; ++nt)
                b2[ks][nt] = fB[(ks * NT + wn * NTW + nt) * 64 + lane];

        f32x4v acc2[MFW][NTW];
#pragma unroll
        for (int mf = 0; mf < MFW; ++mf)
#pragma unroll
            for (int nt = 0; nt < NTW; ++nt) acc2[mf][nt] = (f32x4v)0.0f;

#pragma unroll
        for (int mf = 0; mf < MFW; ++mf) {
            bf16x8 a[KS2];
#pragma unroll
            for (int ks = 0; ks < KS2; ++ks)
                a[ks] = *reinterpret_cast<const bf16x8*>(
                    &buf[((wm * MFW + mf) * 16 + (lane & 15)) * KP2 + ks * 32 + (lane >> 4) * 8]);
#pragma unroll
            for (int nt = 0; nt < NTW; ++nt)
#pragma unroll
                for (int ks = 0; ks < KS2; ++ks)
                    acc2[mf][nt] = __builtin_amdgcn_mfma_f32_16x16x32_bf16(
                        a[ks], __builtin_bit_cast(bf16x8, b2[ks][nt]), acc2[mf][nt], 0, 0, 0);
        }

        float bbv[NTW];
#pragma unroll
        for (int nt = 0; nt < NTW; ++nt) bbv[nt] = bb[(wn * NTW + nt) * 16 + (lane & 15)];

#pragma unroll
        for (int mf = 0; mf < MFW; ++mf)
#pragma unroll
            for (int nt = 0; nt < NTW; ++nt) {
                const f32x4v t = acc2[mf][nt];
                float m0 = fmaxf(fmaxf(t[0], t[1]), fmaxf(t[2], t[3]));
                m0 = fmaxf(m0, __shfl_xor(m0, 16));
                m0 = fmaxf(m0, __shfl_xor(m0, 32));
                const float v = fmaxf(m0 + bbv[nt], 0.0f);
                if (lane < 16)
                    out[(i0 + wm * MFW + mf) * COUT + (wn * NTW + nt) * 16 + lane] = v;
            }
    }
}

extern "C" void kernel_launch(void* const* d_in, const int* in_sizes, int n_in,
                              void* d_out, int out_size, void* d_ws, size_t ws_size,
                              hipStream_t stream)
{
    const float* pos = (const float*)d_in[0];
    const float* W1a = (const float*)d_in[1];
    const float* b1a = (const float*)d_in[2];
    const float* W1b = (const float*)d_in[3];
    const float* b1b = (const float*)d_in[4];
    const float* W2a = (const float*)d_in[5];
    const float* b2a = (const float*)d_in[6];
    const float* W2b = (const float*)d_in[7];
    const float* b2b = (const float*)d_in[8];
    const float* W3a = (const float*)d_in[9];
    const float* b3a = (const float*)d_in[10];
    const float* W3b = (const float*)d_in[11];
    const float* b3b = (const float*)d_in[12];

    float* out = (float*)d_out;
    float* h1 = out;                        // 8192 x 64
    float* h2 = out + N_PTS * 64;           // 8192 x 64
    float* h3 = out + N_PTS * 128;          // 8192 x 128

    int*   idx     = (int*)d_ws;                                   // 512 KB
    uint4* wsFrags = (uint4*)((char*)d_ws + N_PTS * KNN * 4);      // 88 KB

    // pos4 scratch in h3 region (dead before conv3 writes h3)
    float4* pos4 = (float4*)h3;

    prep_all<<<120, 256, 0, stream>>>(pos, pos4, W1a, W1b, W2a, W2b, W3a, W3b, wsFrags);
    knn_kernel<<<N_PTS / QB, 512, 0, stream>>>(pos4, idx);

    const uint4* fW1a = wsFrags + 0 * 64;
    const uint4* fW1b = wsFrags + 4 * 64;
    const uint4* fW2a = wsFrags + 12 * 64;
    const uint4* fW2b = wsFrags + 24 * 64;
    const uint4* fW3a = wsFrags + 32 * 64;
    const uint4* fW3b = wsFrags + 56 * 64;

    conv_mfma<3, 64, 64, 4, 1><<<N_PTS / 8, 256, 0, stream>>>(
        pos, pos, idx, fW1a, b1a, fW1b, b1b, h1);
    conv_mfma<64, 64, 64, 4, 1><<<N_PTS / 8, 256, 0, stream>>>(
        h1, pos, idx, fW2a, b2a, fW2b, b2b, h2);
    conv_mfma<64, 128, 128, 2, 2><<<N_PTS / 8, 256, 0, stream>>>(
        h2, pos, idx, fW3a, b3a, fW3b, b3b, h3);
}

// Round 10
// 76.898 us; speedup vs baseline: 1.0948x; 1.0004x over previous
//
#include <hip/hip_runtime.h>
#include <math.h>

#define N_PTS 8192
#define KNN 16

typedef __attribute__((ext_vector_type(8))) short bf16x8;
typedef __attribute__((ext_vector_type(4))) float f32x4v;

__device__ __forceinline__ unsigned short f2bf(float f)
{
    unsigned u = __float_as_uint(f);
    u = u + 0x7fffu + ((u >> 16) & 1u);       // round-to-nearest-even
    return (unsigned short)(u >> 16);
}
__device__ __forceinline__ unsigned pack2(float a, float b)
{
    return (unsigned)f2bf(a) | ((unsigned)f2bf(b) << 16);
}
__device__ __forceinline__ float rfl(float x)   // force block-uniform value to SGPR
{
    return __int_as_float(__builtin_amdgcn_readfirstlane(__float_as_int(x)));
}

// ---------------------------------------------------------------------------
// prep_all: blocks 0..87 pack weights into MFMA B-frag layout; blocks 88..119
// build pos4 = (x,y,z,|p|^2).
// ---------------------------------------------------------------------------
__global__ __launch_bounds__(256) void prep_all(
    const float* __restrict__ pos, float4* __restrict__ pos4,
    const float* __restrict__ w1a, const float* __restrict__ w1b,
    const float* __restrict__ w2a, const float* __restrict__ w2b,
    const float* __restrict__ w3a, const float* __restrict__ w3b,
    uint4* __restrict__ dst)
{
    const int b = blockIdx.x;
    if (b < 88) {
        if (threadIdx.x >= 64) return;
        const float* Ws[6] = {w1a, w1b, w2a, w2b, w3a, w3b};
        const int Kd[6] = {6, 64, 67, 64, 67, 128};
        const int Nd[6] = {64, 64, 64, 64, 128, 128};
        const int start[7] = {0, 4, 12, 24, 32, 56, 88};
        int m = 0;
        while (b >= start[m + 1]) ++m;
        const int f  = b - start[m];
        const int NT = Nd[m] / 16;
        const int ks = f / NT, nt = f % NT;
        const int lane = threadIdx.x;
        const int c  = nt * 16 + (lane & 15);
        const int k0 = ks * 32 + (lane >> 4) * 8;
        const int K = Kd[m], N = Nd[m];
        const float* W = Ws[m];
        float v[8];
#pragma unroll
        for (int j = 0; j < 8; ++j) {
            const int kk = k0 + j;
            v[j] = (kk < K) ? W[kk * N + c] : 0.0f;
        }
        uint4 o;
        o.x = pack2(v[0], v[1]); o.y = pack2(v[2], v[3]);
        o.z = pack2(v[4], v[5]); o.w = pack2(v[6], v[7]);
        dst[b * 64 + lane] = o;
    } else {
        const int i = (b - 88) * 256 + threadIdx.x;
        const float x = pos[i * 3 + 0];
        const float y = pos[i * 3 + 1];
        const float z = pos[i * 3 + 2];
        pos4[i] = make_float4(x, y, z, fmaf(x, x, fmaf(y, y, z * z)));
    }
}

// ---------------------------------------------------------------------------
// kNN threshold-select, big-tile LDS edition.
// Block = 512 threads (8 waves), QB=16 queries (SGPR, pre-scaled by -2).
// Candidates stream through LDS in 1024-point double-buffered tiles staged
// with global_load_lds (2 stages/thread/tile, wave-contiguous). Each thread
// consumes 2 candidates x 16 queries = 128 VALU per barrier window; 8 tiles
// per pass, 2 passes. Candidate index j = t*1024 + w*128 + {0,64} + lane, so
// j % 64 == lane: the lane partition is preserved and the threshold argument
// is unchanged (T = 16th smallest of the 64 column minima >= true 16th dist;
// 16 smallest column minima are distinct points).
// Cross-wave folding of column minima uses LDS atomicMin on u32 sortkeys
// (strictly monotone bijection -> T bit-identical to the f32 version).
// Pass 2 collects s <= T (exp ~20-30, CAP=128); exact top-16 via LDS
// rank-select on unique keys (sortkey(s)<<32 | j), ties by lowest index.
// ---------------------------------------------------------------------------
__device__ __forceinline__ unsigned sortkey(const float d2)
{
    unsigned u = __float_as_uint(d2);
    u ^= (unsigned)((int)u >> 31) | 0x80000000u;
    return u;
}
__device__ __forceinline__ float unkey(unsigned k)   // inverse of sortkey
{
    const unsigned u = (k & 0x80000000u) ? (k ^ 0x80000000u) : ~k;
    return __uint_as_float(u);
}

constexpr int CAP   = 128;
constexpr int QB    = 16;     // queries per block
constexpr int TILE  = 1024;   // candidates per LDS tile
constexpr int NTL   = N_PTS / TILE;   // 8 tiles

__device__ __forceinline__ void stage_tile(const float4* src, float4* dst)
{
    __builtin_amdgcn_global_load_lds(
        (const __attribute__((address_space(1))) void*)src,
        (__attribute__((address_space(3))) void*)dst, 16, 0, 0);
}

__global__ __launch_bounds__(512) void knn_kernel(const float4* __restrict__ pos4,
                                                  int* __restrict__ idx_out)
{
    __shared__ float4 tile[2][TILE];                 // 32 KB
    __shared__ unsigned minkey[QB][64];              // 4 KB
    __shared__ float Ts[QB];
    __shared__ unsigned long long surv[QB][CAP];     // 16 KB
    __shared__ int scnt[QB];

    const int tid   = threadIdx.x;
    const int w     = tid >> 6;
    const int lane  = tid & 63;
    const int qbase = blockIdx.x * QB;

    if (tid < QB) scnt[tid] = 0;
    reinterpret_cast<unsigned*>(minkey)[tid]       = 0xFFFFFFFFu;
    reinterpret_cast<unsigned*>(minkey)[tid + 512] = 0xFFFFFFFFu;

    float qx[QB], qy[QB], qz[QB];
#pragma unroll
    for (int qi = 0; qi < QB; ++qi) {
        const float4 qp = pos4[qbase + qi];
        qx[qi] = rfl(-2.0f * qp.x);
        qy[qi] = rfl(-2.0f * qp.y);
        qz[qi] = rfl(-2.0f * qp.z);
    }

    const float4* src = pos4 + w * 128 + lane;   // this thread's stage source

    float mn[QB];
#pragma unroll
    for (int qi = 0; qi < QB; ++qi) mn[qi] = 1e30f;

    // ---- pass 1: per-lane min of s over lane partition ----
    stage_tile(src,      &tile[0][w * 128]);
    stage_tile(src + 64, &tile[0][w * 128 + 64]);
    __syncthreads();
#pragma unroll 1
    for (int t = 0; t < NTL; ++t) {
        if (t + 1 < NTL) {
            stage_tile(src + (t + 1) * TILE,      &tile[(t + 1) & 1][w * 128]);
            stage_tile(src + (t + 1) * TILE + 64, &tile[(t + 1) & 1][w * 128 + 64]);
        }
        const float4 p0 = tile[t & 1][w * 128 + lane];
        const float4 p1 = tile[t & 1][w * 128 + 64 + lane];
#pragma unroll
        for (int qi = 0; qi < QB; ++qi) {
            const float s0 = fmaf(qx[qi], p0.x, fmaf(qy[qi], p0.y, fmaf(qz[qi], p0.z, p0.w)));
            const float s1 = fmaf(qx[qi], p1.x, fmaf(qy[qi], p1.y, fmaf(qz[qi], p1.z, p1.w)));
            mn[qi] = fminf(mn[qi], fminf(s0, s1));
        }
        __syncthreads();
    }
#pragma unroll
    for (int qi = 0; qi < QB; ++qi) atomicMin(&minkey[qi][lane], sortkey(mn[qi]));
    __syncthreads();

    // ---- T per query: wave w sorts queries 2w, 2w+1 (u32 bitonic) ----
#pragma unroll
    for (int k = 0; k < 2; ++k) {
        const int q = w * 2 + k;
        unsigned v = minkey[q][lane];
#pragma unroll
        for (int kk = 2; kk <= 64; kk <<= 1)
#pragma unroll
            for (int j = kk >> 1; j > 0; j >>= 1) {
                const unsigned o = __shfl_xor(v, j);
                const bool up = ((lane & kk) == 0);
                const bool lo = ((lane & j) == 0);
                v = (up == lo) ? min(v, o) : max(v, o);
            }
        if (lane == 15) Ts[q] = unkey(v);
    }
    __syncthreads();

    float T[QB];
#pragma unroll
    for (int qi = 0; qi < QB; ++qi) T[qi] = rfl(Ts[qi]);

    // ---- pass 2: collect survivors (same tiling) ----
    stage_tile(src,      &tile[0][w * 128]);
    stage_tile(src + 64, &tile[0][w * 128 + 64]);
    __syncthreads();
#pragma unroll 1
    for (int t = 0; t < NTL; ++t) {
        if (t + 1 < NTL) {
            stage_tile(src + (t + 1) * TILE,      &tile[(t + 1) & 1][w * 128]);
            stage_tile(src + (t + 1) * TILE + 64, &tile[(t + 1) & 1][w * 128 + 64]);
        }
#pragma unroll
        for (int u = 0; u < 2; ++u) {
            const float4 p = tile[t & 1][w * 128 + u * 64 + lane];
            const int j = t * TILE + w * 128 + u * 64 + lane;
#pragma unroll
            for (int qi = 0; qi < QB; ++qi) {
                const float s = fmaf(qx[qi], p.x, fmaf(qy[qi], p.y, fmaf(qz[qi], p.z, p.w)));
                if (s <= T[qi]) {
                    const int slot = atomicAdd(&scnt[qi], 1);
                    if (slot < CAP)
                        surv[qi][slot] = ((unsigned long long)sortkey(s) << 32) | (unsigned)j;
                }
            }
        }
        __syncthreads();
    }

    // ---- exact top-16: wave w ranks queries 2w, 2w+1 (rank = #{key < mine}) ----
#pragma unroll
    for (int k = 0; k < 2; ++k) {
        const int q = w * 2 + k;
        const int n = min(scnt[q], CAP);
        const unsigned long long k0 = (lane < n) ? surv[q][lane] : ~0ull;
        const unsigned long long k1 = (lane + 64 < n) ? surv[q][lane + 64] : ~0ull;
        int r0 = 0, r1 = 0;
#pragma unroll 4
        for (int e = 0; e < n; ++e) {
            const unsigned long long ke = surv[q][e];   // LDS broadcast read
            r0 += (ke < k0) ? 1 : 0;
            r1 += (ke < k1) ? 1 : 0;
        }
        if (lane < n && r0 < KNN)
            idx_out[(qbase + q) * KNN + r0] = (int)(unsigned)(k0 & 0xFFFFFFFFu);
        if (lane + 64 < n && r1 < KNN)
            idx_out[(qbase + q) * KNN + r1] = (int)(unsigned)(k1 & 0xFFFFFFFFu);
    }
}

// ---------------------------------------------------------------------------
// MFMA PointNetConv with LDS aliasing (unchanged from R6-R9): msg (stride KP1)
// and h (stride KP2) share one buffer; GEMM1 accumulates in regs across the
// overwrite barrier. LDS ~35 KB -> 4 blocks/CU.
// ---------------------------------------------------------------------------
template <int CIN, int CMID, int COUT, int WM, int WN>
__global__ __launch_bounds__(256) void conv_mfma(
    const float* __restrict__ x, const float* __restrict__ pos,
    const int* __restrict__ idx,
    const uint4* __restrict__ fA, const float* __restrict__ ba,
    const uint4* __restrict__ fB, const float* __restrict__ bb,
    float* __restrict__ out)
{
    constexpr int PB  = 8, M = 128;
    constexpr int K1  = (CIN + 3 + 31) & ~31;   // 32 or 96
    constexpr int KS1 = K1 / 32;
    constexpr int KP1 = K1 + 8;
    constexpr int KS2 = CMID / 32;
    constexpr int KP2 = CMID + 8;
    constexpr int NT  = COUT / 16;
    constexpr int NTW = NT / WN;                // 4
    constexpr int MFW = (M / 16) / WM;          // 2 or 4
    constexpr int MSGS = M * KP1;               // shorts
    constexpr int HBS  = M * KP2;               // shorts
    constexpr int BUFS = (MSGS > HBS) ? MSGS : HBS;

    __shared__ int nbr[M];
    __shared__ __align__(16) unsigned short buf[BUFS];

    const int tid  = threadIdx.x;
    const int lane = tid & 63;
    const int w    = tid >> 6;
    const int wm   = w / WN, wn = w % WN;
    const int i0   = blockIdx.x * PB;

    if (tid < M) nbr[tid] = idx[i0 * KNN + tid];
    __syncthreads();

    // ---- build msg (bf16), stride KP1 ----
    if constexpr (CIN == 3) {
        if (tid < M) {
            const int row = tid, p = row >> 4, j = nbr[row];
            const float ax = pos[j * 3 + 0], ay = pos[j * 3 + 1], az = pos[j * 3 + 2];
            const float bx = pos[(i0 + p) * 3 + 0], by = pos[(i0 + p) * 3 + 1],
                        bz = pos[(i0 + p) * 3 + 2];
            uint4 c0;
            c0.x = pack2(ax, ay);
            c0.y = pack2(az, ax - bx);
            c0.z = pack2(ay - by, az - bz);
            c0.w = 0u;
            *reinterpret_cast<uint4*>(&buf[row * KP1 + 0])  = c0;
            const uint4 z = make_uint4(0, 0, 0, 0);
            *reinterpret_cast<uint4*>(&buf[row * KP1 + 8])  = z;
            *reinterpret_cast<uint4*>(&buf[row * KP1 + 16]) = z;
            *reinterpret_cast<uint4*>(&buf[row * KP1 + 24]) = z;
        }
    } else {
        const int row = tid >> 1, hh = tid & 1;
        const int j = nbr[row];
        const float* xr = x + j * CIN + hh * 32;
#pragma unroll
        for (int cc = 0; cc < 32; cc += 8) {
            const float4 f0 = *reinterpret_cast<const float4*>(xr + cc);
            const float4 f1 = *reinterpret_cast<const float4*>(xr + cc + 4);
            uint4 o;
            o.x = pack2(f0.x, f0.y); o.y = pack2(f0.z, f0.w);
            o.z = pack2(f1.x, f1.y); o.w = pack2(f1.z, f1.w);
            *reinterpret_cast<uint4*>(&buf[row * KP1 + hh * 32 + cc]) = o;
        }
        if (hh) {
            const int p = row >> 4;
            const float rx = pos[j * 3 + 0] - pos[(i0 + p) * 3 + 0];
            const float ry = pos[j * 3 + 1] - pos[(i0 + p) * 3 + 1];
            const float rz = pos[j * 3 + 2] - pos[(i0 + p) * 3 + 2];
            uint4 c0;
            c0.x = pack2(rx, ry);
            c0.y = pack2(rz, 0.0f);
            c0.z = 0u; c0.w = 0u;
            *reinterpret_cast<uint4*>(&buf[row * KP1 + 64]) = c0;
            const uint4 z = make_uint4(0, 0, 0, 0);
            *reinterpret_cast<uint4*>(&buf[row * KP1 + 72]) = z;
            *reinterpret_cast<uint4*>(&buf[row * KP1 + 80]) = z;
            *reinterpret_cast<uint4*>(&buf[row * KP1 + 88]) = z;
        }
    }
    __syncthreads();

    // ---- GEMM1: acc = msg @ Wa (acc stays in regs) ----
    f32x4v acc[MFW][NTW];
    {
        uint4 b1[KS1][NTW];
#pragma unroll
        for (int ks = 0; ks < KS1; ++ks)
#pragma unroll
            for (int nt = 0; nt < NTW; ++nt)
                b1[ks][nt] = fA[(ks * NT + wn * NTW + nt) * 64 + lane];

#pragma unroll
        for (int mf = 0; mf < MFW; ++mf)
#pragma unroll
            for (int nt = 0; nt < NTW; ++nt) acc[mf][nt] = (f32x4v)0.0f;

#pragma unroll
        for (int mf = 0; mf < MFW; ++mf) {
            bf16x8 a[KS1];
#pragma unroll
            for (int ks = 0; ks < KS1; ++ks)
                a[ks] = *reinterpret_cast<const bf16x8*>(
                    &buf[((wm * MFW + mf) * 16 + (lane & 15)) * KP1 + ks * 32 + (lane >> 4) * 8]);
#pragma unroll
            for (int nt = 0; nt < NTW; ++nt)
#pragma unroll
                for (int ks = 0; ks < KS1; ++ks)
                    acc[mf][nt] = __builtin_amdgcn_mfma_f32_16x16x32_bf16(
                        a[ks], __builtin_bit_cast(bf16x8, b1[ks][nt]), acc[mf][nt], 0, 0, 0);
        }
    }
    __syncthreads();    // all msg reads complete before h overwrites buf

    {   // ---- store h = relu(acc + ba) as bf16, stride KP2 ----
        float bav[NTW];
#pragma unroll
        for (int nt = 0; nt < NTW; ++nt) bav[nt] = ba[(wn * NTW + nt) * 16 + (lane & 15)];
#pragma unroll
        for (int mf = 0; mf < MFW; ++mf)
#pragma unroll
            for (int nt = 0; nt < NTW; ++nt)
#pragma unroll
                for (int r = 0; r < 4; ++r) {
                    const float v = fmaxf(acc[mf][nt][r] + bav[nt], 0.0f);
                    buf[((wm * MFW + mf) * 16 + (lane >> 4) * 4 + r) * KP2 +
                        (wn * NTW + nt) * 16 + (lane & 15)] = f2bf(v);
                }
    }
    __syncthreads();

    // ---- GEMM2: out = relu(max_k(htile @ Wb) + bb) ----
    {
        uint4 b2[KS2][NTW];
#pragma unroll
        for (int ks = 0; ks < KS2; ++ks)
#pragma unroll
            for (int nt = 0; nt < NTW; ++nt)
                b2[ks][nt] = fB[(ks * NT + wn * NTW + nt) * 64 + lane];

        f32x4v acc2[MFW][NTW];
#pragma unroll
        for (int mf = 0; mf < MFW; ++mf)
#pragma unroll
            for (int nt = 0; nt < NTW; ++nt) acc2[mf][nt] = (f32x4v)0.0f;

#pragma unroll
        for (int mf = 0; mf < MFW; ++mf) {
            bf16x8 a[KS2];
#pragma unroll
            for (int ks = 0; ks < KS2; ++ks)
                a[ks] = *reinterpret_cast<const bf16x8*>(
                    &buf[((wm * MFW + mf) * 16 + (lane & 15)) * KP2 + ks * 32 + (lane >> 4) * 8]);
#pragma unroll
            for (int nt = 0; nt < NTW; ++nt)
#pragma unroll
                for (int ks = 0; ks < KS2; ++ks)
                    acc2[mf][nt] = __builtin_amdgcn_mfma_f32_16x16x32_bf16(
                        a[ks], __builtin_bit_cast(bf16x8, b2[ks][nt]), acc2[mf][nt], 0, 0, 0);
        }

        float bbv[NTW];
#pragma unroll
        for (int nt = 0; nt < NTW; ++nt) bbv[nt] = bb[(wn * NTW + nt) * 16 + (lane & 15)];

#pragma unroll
        for (int mf = 0; mf < MFW; ++mf)
#pragma unroll
            for (int nt = 0; nt < NTW; ++nt) {
                const f32x4v t = acc2[mf][nt];
                float m0 = fmaxf(fmaxf(t[0], t[1]), fmaxf(t[2], t[3]));
                m0 = fmaxf(m0, __shfl_xor(m0, 16));
                m0 = fmaxf(m0, __shfl_xor(m0, 32));
                const float v = fmaxf(m0 + bbv[nt], 0.0f);
                if (lane < 16)
                    out[(i0 + wm * MFW + mf) * COUT + (wn * NTW + nt) * 16 + lane] = v;
            }
    }
}

extern "C" void kernel_launch(void* const* d_in, const int* in_sizes, int n_in,
                              void* d_out, int out_size, void* d_ws, size_t ws_size,
                              hipStream_t stream)
{
    const float* pos = (const float*)d_in[0];
    const float* W1a = (const float*)d_in[1];
    const float* b1a = (const float*)d_in[2];
    const float* W1b = (const float*)d_in[3];
    const float* b1b = (const float*)d_in[4];
    const float* W2a = (const float*)d_in[5];
    const float* b2a = (const float*)d_in[6];
    const float* W2b = (const float*)d_in[7];
    const float* b2b = (const float*)d_in[8];
    const float* W3a = (const float*)d_in[9];
    const float* b3a = (const float*)d_in[10];
    const float* W3b = (const float*)d_in[11];
    const float* b3b = (const float*)d_in[12];

    float* out = (float*)d_out;
    float* h1 = out;                        // 8192 x 64
    float* h2 = out + N_PTS * 64;           // 8192 x 64
    float* h3 = out + N_PTS * 128;          // 8192 x 128

    int*   idx     = (int*)d_ws;                                   // 512 KB
    uint4* wsFrags = (uint4*)((char*)d_ws + N_PTS * KNN * 4);      // 88 KB

    // pos4 scratch in h3 region (dead before conv3 writes h3)
    float4* pos4 = (float4*)h3;

    prep_all<<<120, 256, 0, stream>>>(pos, pos4, W1a, W1b, W2a, W2b, W3a, W3b, wsFrags);
    knn_kernel<<<N_PTS / QB, 512, 0, stream>>>(pos4, idx);

    const uint4* fW1a = wsFrags + 0 * 64;
    const uint4* fW1b = wsFrags + 4 * 64;
    const uint4* fW2a = wsFrags + 12 * 64;
    const uint4* fW2b = wsFrags + 24 * 64;
    const uint4* fW3a = wsFrags + 32 * 64;
    const uint4* fW3b = wsFrags + 56 * 64;

    conv_mfma<3, 64, 64, 4, 1><<<N_PTS / 8, 256, 0, stream>>>(
        pos, pos, idx, fW1a, b1a, fW1b, b1b, h1);
    conv_mfma<64, 64, 64, 4, 1><<<N_PTS / 8, 256, 0, stream>>>(
        h1, pos, idx, fW2a, b2a, fW2b, b2b, h2);
    conv_mfma<64, 128, 128, 2, 2><<<N_PTS / 8, 256, 0, stream>>>(
        h2, pos, idx, fW3a, b3a, fW3b, b3b, h3);
}

// Round 11
// 74.243 us; speedup vs baseline: 1.1340x; 1.0358x over previous
//
#include <hip/hip_runtime.h>
#include <math.h>

#define N_PTS 8192
#define KNN 16

typedef __attribute__((ext_vector_type(8))) short bf16x8;
typedef __attribute__((ext_vector_type(4))) float f32x4v;

__device__ __forceinline__ unsigned short f2bf(float f)
{
    unsigned u = __float_as_uint(f);
    u = u + 0x7fffu + ((u >> 16) & 1u);       // round-to-nearest-even
    return (unsigned short)(u >> 16);
}
__device__ __forceinline__ unsigned pack2(float a, float b)
{
    return (unsigned)f2bf(a) | ((unsigned)f2bf(b) << 16);
}
__device__ __forceinline__ float rfl(float x)   // force block-uniform value to SGPR
{
    return __int_as_float(__builtin_amdgcn_readfirstlane(__float_as_int(x)));
}

// ---------------------------------------------------------------------------
// prep_all: blocks 0..87 pack weights into MFMA B-frag layout; blocks 88..119
// build pos4 = (x,y,z,|p|^2).
// ---------------------------------------------------------------------------
__global__ __launch_bounds__(256) void prep_all(
    const float* __restrict__ pos, float4* __restrict__ pos4,
    const float* __restrict__ w1a, const float* __restrict__ w1b,
    const float* __restrict__ w2a, const float* __restrict__ w2b,
    const float* __restrict__ w3a, const float* __restrict__ w3b,
    uint4* __restrict__ dst)
{
    const int b = blockIdx.x;
    if (b < 88) {
        if (threadIdx.x >= 64) return;
        const float* Ws[6] = {w1a, w1b, w2a, w2b, w3a, w3b};
        const int Kd[6] = {6, 64, 67, 64, 67, 128};
        const int Nd[6] = {64, 64, 64, 64, 128, 128};
        const int start[7] = {0, 4, 12, 24, 32, 56, 88};
        int m = 0;
        while (b >= start[m + 1]) ++m;
        const int f  = b - start[m];
        const int NT = Nd[m] / 16;
        const int ks = f / NT, nt = f % NT;
        const int lane = threadIdx.x;
        const int c  = nt * 16 + (lane & 15);
        const int k0 = ks * 32 + (lane >> 4) * 8;
        const int K = Kd[m], N = Nd[m];
        const float* W = Ws[m];
        float v[8];
#pragma unroll
        for (int j = 0; j < 8; ++j) {
            const int kk = k0 + j;
            v[j] = (kk < K) ? W[kk * N + c] : 0.0f;
        }
        uint4 o;
        o.x = pack2(v[0], v[1]); o.y = pack2(v[2], v[3]);
        o.z = pack2(v[4], v[5]); o.w = pack2(v[6], v[7]);
        dst[b * 64 + lane] = o;
    } else {
        const int i = (b - 88) * 256 + threadIdx.x;
        const float x = pos[i * 3 + 0];
        const float y = pos[i * 3 + 1];
        const float z = pos[i * 3 + 2];
        pos4[i] = make_float4(x, y, z, fmaf(x, x, fmaf(y, y, z * z)));
    }
}

// ---------------------------------------------------------------------------
// kNN threshold-select, barrier-free counted-vmcnt edition.
// Block = 512 threads (8 waves), QB=16 queries (SGPR, pre-scaled by -2).
// Candidates stream through LDS in 1024-point double-buffered tiles staged
// with global_load_lds. KEY: thread (w,lane) stages exactly the two float4
// slots it later reads (tile[buf][w*128+lane], [w*128+64+lane]) -> no
// cross-thread LDS sharing in the scan -> NO __syncthreads in the loop.
// Completion is tracked per-wave with counted s_waitcnt vmcnt(2): stage(t+1)
// stays in flight while tile t is consumed (T4 counted-vmcnt, race-free
// degenerate case). Candidate index j = t*1024 + w*128 + {0,64} + lane keeps
// j%64==lane, so the threshold argument is unchanged (T = 16th smallest of
// the 64 column minima >= true 16th distance). Cross-wave folding by LDS
// atomicMin on u32 sortkeys (monotone bijection -> T bit-identical).
// Pass 2 collects s <= T (exp ~20-30, CAP=128); exact top-16 via LDS
// rank-select on unique keys (sortkey(s)<<32 | j), ties by lowest index.
// ---------------------------------------------------------------------------
__device__ __forceinline__ unsigned sortkey(const float d2)
{
    unsigned u = __float_as_uint(d2);
    u ^= (unsigned)((int)u >> 31) | 0x80000000u;
    return u;
}
__device__ __forceinline__ float unkey(unsigned k)   // inverse of sortkey
{
    const unsigned u = (k & 0x80000000u) ? (k ^ 0x80000000u) : ~k;
    return __uint_as_float(u);
}

constexpr int CAP   = 128;
constexpr int QB    = 16;     // queries per block
constexpr int TILE  = 1024;   // candidates per LDS tile
constexpr int NTL   = N_PTS / TILE;   // 8 tiles

__device__ __forceinline__ void stage_tile(const float4* src, float4* dst)
{
    __builtin_amdgcn_global_load_lds(
        (const __attribute__((address_space(1))) void*)src,
        (__attribute__((address_space(3))) void*)dst, 16, 0, 0);
}

__global__ __launch_bounds__(512) void knn_kernel(const float4* __restrict__ pos4,
                                                  int* __restrict__ idx_out)
{
    __shared__ float4 tile[2][TILE];                 // 32 KB
    __shared__ unsigned minkey[QB][64];              // 4 KB
    __shared__ float Ts[QB];
    __shared__ unsigned long long surv[QB][CAP];     // 16 KB
    __shared__ int scnt[QB];

    const int tid   = threadIdx.x;
    const int w     = tid >> 6;
    const int lane  = tid & 63;
    const int qbase = blockIdx.x * QB;

    if (tid < QB) scnt[tid] = 0;
    reinterpret_cast<unsigned*>(minkey)[tid]       = 0xFFFFFFFFu;
    reinterpret_cast<unsigned*>(minkey)[tid + 512] = 0xFFFFFFFFu;

    float qx[QB], qy[QB], qz[QB];
#pragma unroll
    for (int qi = 0; qi < QB; ++qi) {
        const float4 qp = pos4[qbase + qi];
        qx[qi] = rfl(-2.0f * qp.x);
        qy[qi] = rfl(-2.0f * qp.y);
        qz[qi] = rfl(-2.0f * qp.z);
    }

    const float4* src = pos4 + w * 128 + lane;   // this thread's stage source
    float4* dst0 = &tile[0][w * 128];
    float4* dst1 = &tile[1][w * 128];

    float mn[QB];
#pragma unroll
    for (int qi = 0; qi < QB; ++qi) mn[qi] = 1e30f;

    // ---- pass 1: per-lane min of s; barrier-free counted-vmcnt pipeline ----
    stage_tile(src,      dst0);
    stage_tile(src + 64, dst0 + 64);
    __syncthreads();   // orders scnt/minkey init (scan itself needs no barriers)
#pragma unroll 1
    for (int t = 0; t < NTL - 1; ++t) {
        float4* nd = (t & 1) ? dst0 : dst1;
        stage_tile(src + (t + 1) * TILE,      nd);
        stage_tile(src + (t + 1) * TILE + 64, nd + 64);
        asm volatile("s_waitcnt vmcnt(2)" ::: "memory");   // stage(t) done; (t+1) in flight
        __builtin_amdgcn_sched_barrier(0);
        const float4 p0 = tile[t & 1][w * 128 + lane];
        const float4 p1 = tile[t & 1][w * 128 + 64 + lane];
#pragma unroll
        for (int qi = 0; qi < QB; ++qi) {
            const float s0 = fmaf(qx[qi], p0.x, fmaf(qy[qi], p0.y, fmaf(qz[qi], p0.z, p0.w)));
            const float s1 = fmaf(qx[qi], p1.x, fmaf(qy[qi], p1.y, fmaf(qz[qi], p1.z, p1.w)));
            mn[qi] = fminf(mn[qi], fminf(s0, s1));
        }
    }
    {   // final window
        asm volatile("s_waitcnt vmcnt(0)" ::: "memory");
        __builtin_amdgcn_sched_barrier(0);
        const int t = NTL - 1;
        const float4 p0 = tile[t & 1][w * 128 + lane];
        const float4 p1 = tile[t & 1][w * 128 + 64 + lane];
#pragma unroll
        for (int qi = 0; qi < QB; ++qi) {
            const float s0 = fmaf(qx[qi], p0.x, fmaf(qy[qi], p0.y, fmaf(qz[qi], p0.z, p0.w)));
            const float s1 = fmaf(qx[qi], p1.x, fmaf(qy[qi], p1.y, fmaf(qz[qi], p1.z, p1.w)));
            mn[qi] = fminf(mn[qi], fminf(s0, s1));
        }
    }
#pragma unroll
    for (int qi = 0; qi < QB; ++qi) atomicMin(&minkey[qi][lane], sortkey(mn[qi]));
    __syncthreads();

    // ---- T per query: wave w sorts queries 2w, 2w+1 (u32 bitonic) ----
#pragma unroll
    for (int k = 0; k < 2; ++k) {
        const int q = w * 2 + k;
        unsigned v = minkey[q][lane];
#pragma unroll
        for (int kk = 2; kk <= 64; kk <<= 1)
#pragma unroll
            for (int j = kk >> 1; j > 0; j >>= 1) {
                const unsigned o = __shfl_xor(v, j);
                const bool up = ((lane & kk) == 0);
                const bool lo = ((lane & j) == 0);
                v = (up == lo) ? min(v, o) : max(v, o);
            }
        if (lane == 15) Ts[q] = unkey(v);
    }
    __syncthreads();

    float T[QB];
#pragma unroll
    for (int qi = 0; qi < QB; ++qi) T[qi] = rfl(Ts[qi]);

    // ---- pass 2: collect survivors (same barrier-free pipeline) ----
    stage_tile(src,      dst0);
    stage_tile(src + 64, dst0 + 64);
#pragma unroll 1
    for (int t = 0; t < NTL - 1; ++t) {
        float4* nd = (t & 1) ? dst0 : dst1;
        stage_tile(src + (t + 1) * TILE,      nd);
        stage_tile(src + (t + 1) * TILE + 64, nd + 64);
        asm volatile("s_waitcnt vmcnt(2)" ::: "memory");
        __builtin_amdgcn_sched_barrier(0);
#pragma unroll
        for (int u = 0; u < 2; ++u) {
            const float4 p = tile[t & 1][w * 128 + u * 64 + lane];
            const int j = t * TILE + w * 128 + u * 64 + lane;
#pragma unroll
            for (int qi = 0; qi < QB; ++qi) {
                const float s = fmaf(qx[qi], p.x, fmaf(qy[qi], p.y, fmaf(qz[qi], p.z, p.w)));
                if (s <= T[qi]) {
                    const int slot = atomicAdd(&scnt[qi], 1);
                    if (slot < CAP)
                        surv[qi][slot] = ((unsigned long long)sortkey(s) << 32) | (unsigned)j;
                }
            }
        }
    }
    {   // final window
        asm volatile("s_waitcnt vmcnt(0)" ::: "memory");
        __builtin_amdgcn_sched_barrier(0);
        const int t = NTL - 1;
#pragma unroll
        for (int u = 0; u < 2; ++u) {
            const float4 p = tile[t & 1][w * 128 + u * 64 + lane];
            const int j = t * TILE + w * 128 + u * 64 + lane;
#pragma unroll
            for (int qi = 0; qi < QB; ++qi) {
                const float s = fmaf(qx[qi], p.x, fmaf(qy[qi], p.y, fmaf(qz[qi], p.z, p.w)));
                if (s <= T[qi]) {
                    const int slot = atomicAdd(&scnt[qi], 1);
                    if (slot < CAP)
                        surv[qi][slot] = ((unsigned long long)sortkey(s) << 32) | (unsigned)j;
                }
            }
        }
    }
    __syncthreads();

    // ---- exact top-16: wave w ranks queries 2w, 2w+1 (rank = #{key < mine}) ----
#pragma unroll
    for (int k = 0; k < 2; ++k) {
        const int q = w * 2 + k;
        const int n = min(scnt[q], CAP);
        const unsigned long long k0 = (lane < n) ? surv[q][lane] : ~0ull;
        const unsigned long long k1 = (lane + 64 < n) ? surv[q][lane + 64] : ~0ull;
        int r0 = 0, r1 = 0;
#pragma unroll 4
        for (int e = 0; e < n; ++e) {
            const unsigned long long ke = surv[q][e];   // LDS broadcast read
            r0 += (ke < k0) ? 1 : 0;
            r1 += (ke < k1) ? 1 : 0;
        }
        if (lane < n && r0 < KNN)
            idx_out[(qbase + q) * KNN + r0] = (int)(unsigned)(k0 & 0xFFFFFFFFu);
        if (lane + 64 < n && r1 < KNN)
            idx_out[(qbase + q) * KNN + r1] = (int)(unsigned)(k1 & 0xFFFFFFFFu);
    }
}

// ---------------------------------------------------------------------------
// MFMA PointNetConv with LDS aliasing (unchanged from R6-R10): msg (stride
// KP1) and h (stride KP2) share one buffer; GEMM1 accumulates in regs across
// the overwrite barrier. LDS ~35 KB -> 4 blocks/CU.
// ---------------------------------------------------------------------------
template <int CIN, int CMID, int COUT, int WM, int WN>
__global__ __launch_bounds__(256) void conv_mfma(
    const float* __restrict__ x, const float* __restrict__ pos,
    const int* __restrict__ idx,
    const uint4* __restrict__ fA, const float* __restrict__ ba,
    const uint4* __restrict__ fB, const float* __restrict__ bb,
    float* __restrict__ out)
{
    constexpr int PB  = 8, M = 128;
    constexpr int K1  = (CIN + 3 + 31) & ~31;   // 32 or 96
    constexpr int KS1 = K1 / 32;
    constexpr int KP1 = K1 + 8;
    constexpr int KS2 = CMID / 32;
    constexpr int KP2 = CMID + 8;
    constexpr int NT  = COUT / 16;
    constexpr int NTW = NT / WN;                // 4
    constexpr int MFW = (M / 16) / WM;          // 2 or 4
    constexpr int MSGS = M * KP1;               // shorts
    constexpr int HBS  = M * KP2;               // shorts
    constexpr int BUFS = (MSGS > HBS) ? MSGS : HBS;

    __shared__ int nbr[M];
    __shared__ __align__(16) unsigned short buf[BUFS];

    const int tid  = threadIdx.x;
    const int lane = tid & 63;
    const int w    = tid >> 6;
    const int wm   = w / WN, wn = w % WN;
    const int i0   = blockIdx.x * PB;

    if (tid < M) nbr[tid] = idx[i0 * KNN + tid];
    __syncthreads();

    // ---- build msg (bf16), stride KP1 ----
    if constexpr (CIN == 3) {
        if (tid < M) {
            const int row = tid, p = row >> 4, j = nbr[row];
            const float ax = pos[j * 3 + 0], ay = pos[j * 3 + 1], az = pos[j * 3 + 2];
            const float bx = pos[(i0 + p) * 3 + 0], by = pos[(i0 + p) * 3 + 1],
                        bz = pos[(i0 + p) * 3 + 2];
            uint4 c0;
            c0.x = pack2(ax, ay);
            c0.y = pack2(az, ax - bx);
            c0.z = pack2(ay - by, az - bz);
            c0.w = 0u;
            *reinterpret_cast<uint4*>(&buf[row * KP1 + 0])  = c0;
            const uint4 z = make_uint4(0, 0, 0, 0);
            *reinterpret_cast<uint4*>(&buf[row * KP1 + 8])  = z;
            *reinterpret_cast<uint4*>(&buf[row * KP1 + 16]) = z;
            *reinterpret_cast<uint4*>(&buf[row * KP1 + 24]) = z;
        }
    } else {
        const int row = tid >> 1, hh = tid & 1;
        const int j = nbr[row];
        const float* xr = x + j * CIN + hh * 32;
#pragma unroll
        for (int cc = 0; cc < 32; cc += 8) {
            const float4 f0 = *reinterpret_cast<const float4*>(xr + cc);
            const float4 f1 = *reinterpret_cast<const float4*>(xr + cc + 4);
            uint4 o;
            o.x = pack2(f0.x, f0.y); o.y = pack2(f0.z, f0.w);
            o.z = pack2(f1.x, f1.y); o.w = pack2(f1.z, f1.w);
            *reinterpret_cast<uint4*>(&buf[row * KP1 + hh * 32 + cc]) = o;
        }
        if (hh) {
            const int p = row >> 4;
            const float rx = pos[j * 3 + 0] - pos[(i0 + p) * 3 + 0];
            const float ry = pos[j * 3 + 1] - pos[(i0 + p) * 3 + 1];
            const float rz = pos[j * 3 + 2] - pos[(i0 + p) * 3 + 2];
            uint4 c0;
            c0.x = pack2(rx, ry);
            c0.y = pack2(rz, 0.0f);
            c0.z = 0u; c0.w = 0u;
            *reinterpret_cast<uint4*>(&buf[row * KP1 + 64]) = c0;
            const uint4 z = make_uint4(0, 0, 0, 0);
            *reinterpret_cast<uint4*>(&buf[row * KP1 + 72]) = z;
            *reinterpret_cast<uint4*>(&buf[row * KP1 + 80]) = z;
            *reinterpret_cast<uint4*>(&buf[row * KP1 + 88]) = z;
        }
    }
    __syncthreads();

    // ---- GEMM1: acc = msg @ Wa (acc stays in regs) ----
    f32x4v acc[MFW][NTW];
    {
        uint4 b1[KS1][NTW];
#pragma unroll
        for (int ks = 0; ks < KS1; ++ks)
#pragma unroll
            for (int nt = 0; nt < NTW; ++nt)
                b1[ks][nt] = fA[(ks * NT + wn * NTW + nt) * 64 + lane];

#pragma unroll
        for (int mf = 0; mf < MFW; ++mf)
#pragma unroll
            for (int nt = 0; nt < NTW; ++nt) acc[mf][nt] = (f32x4v)0.0f;

#pragma unroll
        for (int mf = 0; mf < MFW; ++mf) {
            bf16x8 a[KS1];
#pragma unroll
            for (int ks = 0; ks < KS1; ++ks)
                a[ks] = *reinterpret_cast<const bf16x8*>(
                    &buf[((wm * MFW + mf) * 16 + (lane & 15)) * KP1 + ks * 32 + (lane >> 4) * 8]);
#pragma unroll
            for (int nt = 0; nt < NTW; ++nt)
#pragma unroll
                for (int ks = 0; ks < KS1; ++ks)
                    acc[mf][nt] = __builtin_amdgcn_mfma_f32_16x16x32_bf16(
                        a[ks], __builtin_bit_cast(bf16x8, b1[ks][nt]), acc[mf][nt], 0, 0, 0);
        }
    }
    __syncthreads();    // all msg reads complete before h overwrites buf

    {   // ---- store h = relu(acc + ba) as bf16, stride KP2 ----
        float bav[NTW];
#pragma unroll
        for (int nt = 0; nt < NTW; ++nt) bav[nt] = ba[(wn * NTW + nt) * 16 + (lane & 15)];
#pragma unroll
        for (int mf = 0; mf < MFW; ++mf)
#pragma unroll
            for (int nt = 0; nt < NTW; ++nt)
#pragma unroll
                for (int r = 0; r < 4; ++r) {
                    const float v = fmaxf(acc[mf][nt][r] + bav[nt], 0.0f);
                    buf[((wm * MFW + mf) * 16 + (lane >> 4) * 4 + r) * KP2 +
                        (wn * NTW + nt) * 16 + (lane & 15)] = f2bf(v);
                }
    }
    __syncthreads();

    // ---- GEMM2: out = relu(max_k(htile @ Wb) + bb) ----
    {
        uint4 b2[KS2][NTW];
#pragma unroll
        for (int ks = 0; ks < KS2; ++ks)
#pragma unroll
            for (int nt = 0; nt < NTW; ++nt)
                b2[ks][nt] = fB[(ks * NT + wn * NTW + nt) * 64 + lane];

        f32x4v acc2[MFW][NTW];
#pragma unroll
        for (int mf = 0; mf < MFW; ++mf)
#pragma unroll
            for (int nt = 0; nt < NTW; ++nt) acc2[mf][nt] = (f32x4v)0.0f;

#pragma unroll
        for (int mf = 0; mf < MFW; ++mf) {
            bf16x8 a[KS2];
#pragma unroll
            for (int ks = 0; ks < KS2; ++ks)
                a[ks] = *reinterpret_cast<const bf16x8*>(
                    &buf[((wm * MFW + mf) * 16 + (lane & 15)) * KP2 + ks * 32 + (lane >> 4) * 8]);
#pragma unroll
            for (int nt = 0; nt < NTW; ++nt)
#pragma unroll
                for (int ks = 0; ks < KS2; ++ks)
                    acc2[mf][nt] = __builtin_amdgcn_mfma_f32_16x16x32_bf16(
                        a[ks], __builtin_bit_cast(bf16x8, b2[ks][nt]), acc2[mf][nt], 0, 0, 0);
        }

        float bbv[NTW];
#pragma unroll
        for (int nt = 0; nt < NTW; ++nt) bbv[nt] = bb[(wn * NTW + nt) * 16 + (lane & 15)];

#pragma unroll
        for (int mf = 0; mf < MFW; ++mf)
#pragma unroll
            for (int nt = 0; nt < NTW; ++nt) {
                const f32x4v t = acc2[mf][nt];
                float m0 = fmaxf(fmaxf(t[0], t[1]), fmaxf(t[2], t[3]));
                m0 = fmaxf(m0, __shfl_xor(m0, 16));
                m0 = fmaxf(m0, __shfl_xor(m0, 32));
                const float v = fmaxf(m0 + bbv[nt], 0.0f);
                if (lane < 16)
                    out[(i0 + wm * MFW + mf) * COUT + (wn * NTW + nt) * 16 + lane] = v;
            }
    }
}

extern "C" void kernel_launch(void* const* d_in, const int* in_sizes, int n_in,
                              void* d_out, int out_size, void* d_ws, size_t ws_size,
                              hipStream_t stream)
{
    const float* pos = (const float*)d_in[0];
    const float* W1a = (const float*)d_in[1];
    const float* b1a = (const float*)d_in[2];
    const float* W1b = (const float*)d_in[3];
    const float* b1b = (const float*)d_in[4];
    const float* W2a = (const float*)d_in[5];
    const float* b2a = (const float*)d_in[6];
    const float* W2b = (const float*)d_in[7];
    const float* b2b = (const float*)d_in[8];
    const float* W3a = (const float*)d_in[9];
    const float* b3a = (const float*)d_in[10];
    const float* W3b = (const float*)d_in[11];
    const float* b3b = (const float*)d_in[12];

    float* out = (float*)d_out;
    float* h1 = out;                        // 8192 x 64
    float* h2 = out + N_PTS * 64;           // 8192 x 64
    float* h3 = out + N_PTS * 128;          // 8192 x 128

    int*   idx     = (int*)d_ws;                                   // 512 KB
    uint4* wsFrags = (uint4*)((char*)d_ws + N_PTS * KNN * 4);      // 88 KB

    // pos4 scratch in h3 region (dead before conv3 writes h3)
    float4* pos4 = (float4*)h3;

    prep_all<<<120, 256, 0, stream>>>(pos, pos4, W1a, W1b, W2a, W2b, W3a, W3b, wsFrags);
    knn_kernel<<<N_PTS / QB, 512, 0, stream>>>(pos4, idx);

    const uint4* fW1a = wsFrags + 0 * 64;
    const uint4* fW1b = wsFrags + 4 * 64;
    const uint4* fW2a = wsFrags + 12 * 64;
    const uint4* fW2b = wsFrags + 24 * 64;
    const uint4* fW3a = wsFrags + 32 * 64;
    const uint4* fW3b = wsFrags + 56 * 64;

    conv_mfma<3, 64, 64, 4, 1><<<N_PTS / 8, 256, 0, stream>>>(
        pos, pos, idx, fW1a, b1a, fW1b, b1b, h1);
    conv_mfma<64, 64, 64, 4, 1><<<N_PTS / 8, 256, 0, stream>>>(
        h1, pos, idx, fW2a, b2a, fW2b, b2b, h2);
    conv_mfma<64, 128, 128, 2, 2><<<N_PTS / 8, 256, 0, stream>>>(
        h2, pos, idx, fW3a, b3a, fW3b, b3b, h3);
}